// Round 9
// baseline (418.118 us; speedup 1.0000x reference)
//
#include <hip/hip_runtime.h>
#include <hip/hip_bf16.h>

using bf16x8 = __bf16 __attribute__((ext_vector_type(8)));
using f32x4  = float  __attribute__((ext_vector_type(4)));
using u16x8  = unsigned short __attribute__((ext_vector_type(8)));
using u16x4  = unsigned short __attribute__((ext_vector_type(4)));

__device__ __forceinline__ unsigned short f2bf(float f) {
  unsigned u = __builtin_bit_cast(unsigned, f);
  u += 0x7fffu + ((u >> 16) & 1u);
  return (unsigned short)(u >> 16);
}
__device__ __forceinline__ float bf2f(unsigned short h) {
  return __builtin_bit_cast(float, (unsigned)h << 16);
}

__device__ __forceinline__ void gload16(const void* g, void* l) {
  __builtin_amdgcn_global_load_lds(
      (const __attribute__((address_space(1))) void*)g,
      (__attribute__((address_space(3))) void*)l, 16, 0, 0);
}

__device__ __forceinline__ void barrier_raw() {
  asm volatile("" ::: "memory");
  __builtin_amdgcn_s_barrier();
  asm volatile("" ::: "memory");
}
#define VMC4() asm volatile("s_waitcnt vmcnt(4)" ::: "memory")

// ---------------- convert f32 -> bf16 (vectorized) ----------------
__global__ __launch_bounds__(256) void conv_f32_bf16(const float* __restrict__ in,
                                                     unsigned short* __restrict__ out, int n) {
  int stride = gridDim.x * 256 * 4;
  for (int i = (blockIdx.x * 256 + threadIdx.x) * 4; i < n; i += stride) {
    float4 v = *reinterpret_cast<const float4*>(in + i);
    u16x4 o = { f2bf(v.x), f2bf(v.y), f2bf(v.z), f2bf(v.w) };
    *reinterpret_cast<u16x4*>(out + i) = o;
  }
}

// ---------------- transpose + convert: out[c][r] = bf16(in[r][c]) ----------------
__global__ __launch_bounds__(256) void transpose_f32_bf16(const float* __restrict__ in,
                                                          unsigned short* __restrict__ out,
                                                          int R, int C) {
  __shared__ float t[64][65];
  int c0 = blockIdx.x * 64, r0 = blockIdx.y * 64;
  int lx = threadIdx.x & 63, ly = threadIdx.x >> 6;
#pragma unroll
  for (int i = 0; i < 16; ++i) {
    int r = ly * 16 + i;
    t[r][lx] = in[(size_t)(r0 + r) * C + c0 + lx];
  }
  __syncthreads();
#pragma unroll
  for (int i = 0; i < 16; ++i) {
    int c = ly * 16 + i;
    out[(size_t)(c0 + c) * R + r0 + lx] = f2bf(t[lx][c]);
  }
}

// ======== 256x256, BK=64, 8-wave GEMM: A via LDS (dbuf 2x32KB), B DIRECT from
// global (VMEM pipe). B^T rows are contiguous in k, so a B fragment (n,kk) is a
// 16B global load at row (bcol+wc*64+n*16+lr), byte t*128+kk*64+kg*16; all kg/kk
// accesses of a row hit ONE 128B line per K-step (L1-line-perfect, L2-resident
// via the tn-shared panel). This moves ~1/3 of LDS-pipe traffic (64KB reads +
// 32KB writes per CU-K-step) to the otherwise-idle VMEM pipe; LDS now serves
// A only (128KB/CU-K-step < MFMA 2480cyc). One barrier per K-step.
// vmcnt ledger (per wave, steady state): P1 issues bH(t)x4 then A(t+1)-stage x4
// -> compiler's bH wait before Q02 = vmcnt(4) (A stays in flight); P3 issues
// bL(t+1)x4; P4 manual VMC4 drains exactly A(t+1), leaves bL(t+1) in flight;
// barrier makes buf(t+1) visible; READ aQ(t+1).
__device__ __forceinline__ void gemm256_mainloop(
    const unsigned short* __restrict__ A, const unsigned short* __restrict__ Bt,
    int brow, int bcol, char* lds, f32x4 (&acc)[8][4]) {
  constexpr int NT = 16;  // K = 1024 / 64
  const int tid  = threadIdx.x;
  const int lane = tid & 63;
  const int w    = tid >> 6;
  const int wr   = w >> 2, wc = w & 3;
  const int lr   = lane & 15, kg = lane >> 4;

  // A staging: LDS dest linear (tid*16); global source inverse-swizzled
  const int o0 = tid * 16;
  const int p0 = o0 ^ (((o0 >> 7) & 7) << 4);
  const int off0 = (p0 >> 7) * 2048 + (p0 & 127);
  const int wq = w << 10;

  // swizzled A read addressing: ck1 = ck0 ^ 64
  const int xr  = (lr & 7) << 4;
  const int ck0 = (kg * 16) ^ xr;
  const int aoff = wr * 16384 + lr * 128;

  const char* rA00 = lds + aoff + ck0;
  const char* rA01 = lds + aoff + (ck0 ^ 64);
  const char* rA10 = rA00 + 32768;
  const char* rA11 = rA01 + 32768;

  const char* gA0 = (const char*)(A + (size_t)brow * 1024) + off0;
  const char* gA1 = (const char*)(A + (size_t)(brow + 128) * 1024) + off0;

  // B per-lane row pointers (include kg*16); frag (n,kk,t) at +t*128+kk*64
  const char* gB[4];
#pragma unroll
  for (int n = 0; n < 4; ++n)
    gB[n] = (const char*)(Bt + (size_t)(bcol + wc * 64 + n * 16 + lr) * 1024) + kg * 16;

  auto STG = [&](const char*& g, int region) {
    gload16(g, lds + region + wq);
    gload16(g + 131072, lds + region + 8192 + wq);  // rows 64-127 (+64*2048)
    g += 128;                                        // next K-step
  };

  bf16x8 aQ[4][2], aR[4][2], bL0[2][2], bL1[2][2], bH[2][2];

  auto READ_A = [&](bf16x8 (&dst)[4][2], const char* pk0, const char* pk1, int mb) {
#pragma unroll
    for (int m = 0; m < 4; ++m) {
      dst[m][0] = __builtin_bit_cast(bf16x8, *(const u16x8*)(pk0 + (mb + m) * 2048));
      dst[m][1] = __builtin_bit_cast(bf16x8, *(const u16x8*)(pk1 + (mb + m) * 2048));
    }
  };
  auto GLOAD_B = [&](bf16x8 (&dst)[2][2], int nb, int tbytes) {
#pragma unroll
    for (int n = 0; n < 2; ++n) {
      dst[n][0] = __builtin_bit_cast(bf16x8, *(const u16x8*)(gB[nb + n] + tbytes));
      dst[n][1] = __builtin_bit_cast(bf16x8, *(const u16x8*)(gB[nb + n] + tbytes + 64));
    }
  };
  auto MFMA_Q = [&](int mb, int nb, bf16x8 (&Af)[4][2], bf16x8 (&Bf)[2][2]) {
    __builtin_amdgcn_s_setprio(1);
#pragma unroll
    for (int kk = 0; kk < 2; ++kk)
#pragma unroll
      for (int m = 0; m < 4; ++m)
#pragma unroll
        for (int n = 0; n < 2; ++n)
          acc[mb + m][nb + n] =
              __builtin_amdgcn_mfma_f32_16x16x32_bf16(Af[m][kk], Bf[n][kk], acc[mb + m][nb + n], 0, 0, 0);
    __builtin_amdgcn_s_setprio(0);
  };

  // ---- prologue: A(0)->buf0, bL(0) from global ----
  STG(gA0, 0); STG(gA1, 16384);
  GLOAD_B(bL0, 0, 0);
  VMC4();          // drain A(0)'s 4 loads; bL0 awaited by compiler at Q00
  barrier_raw();
  READ_A(aQ, rA00, rA01, 0);

  for (int t = 0; t < NT; t += 2) {
    // ================= even iter: cur=buf0, nxt=buf1 =================
    // P1: B-high(t) loads first (so compiler's wait leaves A-stage in flight)
    GLOAD_B(bH, 2, t << 7);
    if (t + 1 < NT) { STG(gA0, 32768); STG(gA1, 49152); }  // A(t+1)->buf1
    MFMA_Q(0, 0, aQ, bL0);                                 // Q00
    // P2
    READ_A(aR, rA00, rA01, 4);
    MFMA_Q(0, 2, aQ, bH);                                  // Q02
    // P3
    if (t + 1 < NT) GLOAD_B(bL1, 0, (t + 1) << 7);         // bL(t+1)
    MFMA_Q(4, 2, aR, bH);                                  // Q42
    // P4: drain A(t+1) only; single barrier per K-step
    if (t + 1 < NT) VMC4();
    barrier_raw();
    if (t + 1 < NT) READ_A(aQ, rA10, rA11, 0);
    MFMA_Q(4, 0, aR, bL0);                                 // Q40

    // ================= odd iter t+1: cur=buf1, nxt=buf0 =================
    if (t + 1 < NT) {
      GLOAD_B(bH, 2, (t + 1) << 7);
      if (t + 2 < NT) { STG(gA0, 0); STG(gA1, 16384); }    // A(t+2)->buf0
      MFMA_Q(0, 0, aQ, bL1);
      READ_A(aR, rA10, rA11, 4);
      MFMA_Q(0, 2, aQ, bH);
      if (t + 2 < NT) GLOAD_B(bL0, 0, (t + 2) << 7);
      MFMA_Q(4, 2, aR, bH);
      if (t + 2 < NT) VMC4();
      barrier_raw();
      if (t + 2 < NT) READ_A(aQ, rA00, rA01, 0);
      MFMA_Q(4, 0, aR, bL1);
    }
  }
}

// ---------------- GEMM1: qkv = x @ W_qkv, epilogue elu+1 on q,k; scatter (B,H,N,D) ----------------
__global__ __launch_bounds__(512, 2) void gemm_qkv(
    const unsigned short* __restrict__ xbf, const unsigned short* __restrict__ wt,
    unsigned short* __restrict__ q, unsigned short* __restrict__ k, unsigned short* __restrict__ v) {
  __shared__ __align__(16) char lds[65536];
  f32x4 acc[8][4] = {};
  // L2-patch grid: XCD r owns tm stripe [8r,8r+8), tn-major within the stripe.
  const int bid = blockIdx.x;                    // 768 = 8 XCD x 8 tm x 12 tn
  const int r = bid & 7, i = bid >> 3;
  const int tm = r * 8 + (i & 7);
  const int tn = i >> 3;
  const int brow = tm * 256, bcol = tn * 256;
  gemm256_mainloop(xbf, wt, brow, bcol, lds, acc);

  const int lane = threadIdx.x & 63, w = threadIdx.x >> 6;
  const int wr = w >> 2, wc = w & 3;
  const int lr = lane & 15, kg = lane >> 4;
#pragma unroll
  for (int m = 0; m < 8; ++m)
#pragma unroll
    for (int n = 0; n < 4; ++n)
#pragma unroll
      for (int rr = 0; rr < 4; ++rr) {
        int grow = brow + wr * 128 + m * 16 + kg * 4 + rr;
        int gcol = bcol + wc * 64 + n * 16 + lr;
        float val = acc[m][n][rr];
        int tt = gcol >> 10;
        int h = (gcol >> 6) & 15;
        int d = gcol & 63;
        int b = grow >> 12, s = grow & 4095;
        size_t idx = ((size_t)(b * 16 + h) * 4096 + s) * 64 + d;
        if (tt < 2) {
          val = val > 0.f ? val + 1.f : __expf(val);  // elu(x)+1
          (tt == 0 ? q : k)[idx] = f2bf(val);
        } else {
          v[idx] = f2bf(val);
        }
      }
}

// ---------------- GEMM2: out = attn @ W_out + b ----------------
__global__ __launch_bounds__(512, 2) void gemm_out(
    const unsigned short* __restrict__ attn, const unsigned short* __restrict__ wt,
    const float* __restrict__ bias, float* __restrict__ out) {
  __shared__ __align__(16) char lds[65536];
  f32x4 acc[8][4] = {};
  const int bid = blockIdx.x;                    // 256 = 8 XCD x 8 tm x 4 tn
  const int r = bid & 7, i = bid >> 3;
  const int tm = r * 8 + (i & 7);
  const int tn = i >> 3;
  const int brow = tm * 256, bcol = tn * 256;
  gemm256_mainloop(attn, wt, brow, bcol, lds, acc);

  const int lane = threadIdx.x & 63, w = threadIdx.x >> 6;
  const int wr = w >> 2, wc = w & 3;
  const int lr = lane & 15, kg = lane >> 4;
#pragma unroll
  for (int m = 0; m < 8; ++m)
#pragma unroll
    for (int n = 0; n < 4; ++n)
#pragma unroll
      for (int rr = 0; rr < 4; ++rr) {
        int grow = brow + wr * 128 + m * 16 + kg * 4 + rr;
        int gcol = bcol + wc * 64 + n * 16 + lr;
        out[(size_t)grow * 1024 + gcol] = acc[m][n][rr] + bias[gcol];
      }
}

// ---------------- kv[d][e] = sum_n k[n][d] v[n][e]  (stored [e][d]); ksum[d] ----------------
__global__ __launch_bounds__(256) void kv_kernel(
    const unsigned short* __restrict__ k, const unsigned short* __restrict__ v,
    float* __restrict__ kv, float* __restrict__ ksum) {
  const int bid = blockIdx.x;             // B*H*8 = 512
  const int bh = bid >> 3, chunk = bid & 7;
  const unsigned short* kb = k + (size_t)bh * 4096 * 64 + chunk * 512 * 64;
  const unsigned short* vb = v + (size_t)bh * 4096 * 64 + chunk * 512 * 64;
  __shared__ unsigned short ks[64 * 64];
  __shared__ unsigned short vs[64 * 64];
  const int tid = threadIdx.x;
  const int ty = tid >> 4, tx = tid & 15;
  float acc[4][4] = {};
  float ksacc[4] = {};
  for (int t = 0; t < 8; ++t) {
    const unsigned short* ksrc = kb + t * 4096;
    const unsigned short* vsrc = vb + t * 4096;
    *reinterpret_cast<u16x8*>(&ks[tid * 8])        = *reinterpret_cast<const u16x8*>(ksrc + tid * 8);
    *reinterpret_cast<u16x8*>(&ks[2048 + tid * 8]) = *reinterpret_cast<const u16x8*>(ksrc + 2048 + tid * 8);
    *reinterpret_cast<u16x8*>(&vs[tid * 8])        = *reinterpret_cast<const u16x8*>(vsrc + tid * 8);
    *reinterpret_cast<u16x8*>(&vs[2048 + tid * 8]) = *reinterpret_cast<const u16x8*>(vsrc + 2048 + tid * 8);
    __syncthreads();
#pragma unroll 4
    for (int nn = 0; nn < 64; ++nn) {
      u16x4 ku = *reinterpret_cast<const u16x4*>(&ks[nn * 64 + ty * 4]);
      u16x4 vu = *reinterpret_cast<const u16x4*>(&vs[nn * 64 + tx * 4]);
      float kd[4], ve[4];
#pragma unroll
      for (int i = 0; i < 4; ++i) { kd[i] = bf2f(ku[i]); ve[i] = bf2f(vu[i]); }
#pragma unroll
      for (int i = 0; i < 4; ++i) ksacc[i] += kd[i];
#pragma unroll
      for (int i = 0; i < 4; ++i)
#pragma unroll
        for (int j = 0; j < 4; ++j) acc[i][j] += kd[i] * ve[j];
    }
    __syncthreads();
  }
  float* kvb = kv + (size_t)bh * 4096;
#pragma unroll
  for (int i = 0; i < 4; ++i)
#pragma unroll
    for (int j = 0; j < 4; ++j)
      atomicAdd(&kvb[(tx * 4 + j) * 64 + ty * 4 + i], acc[i][j]);  // [e][d]
  if (tx == 0) {
#pragma unroll
    for (int i = 0; i < 4; ++i) atomicAdd(&ksum[bh * 64 + ty * 4 + i], ksacc[i]);
  }
}

// ---------------- num = q @ kv ; attn = num / (q.ksum + 1e-6) ----------------
__global__ __launch_bounds__(256) void num_kernel(
    const unsigned short* __restrict__ q, const float* __restrict__ kv,
    const float* __restrict__ ksum, unsigned short* __restrict__ attn) {
  const int bid = blockIdx.x;              // B*H*64 = 4096
  const int bh = bid >> 6, sblk = bid & 63;
  const int b = bh >> 4, h = bh & 15;
  __shared__ unsigned short kvs[64 * 72];
  __shared__ float ksum_s[64];
  __shared__ float norm_s[64];
  const int tid = threadIdx.x;
  const float* kvb = kv + (size_t)bh * 4096;
#pragma unroll
  for (int r = 0; r < 4; ++r) {
    int e = r * 1024 + tid * 4;
    float4 f = *reinterpret_cast<const float4*>(&kvb[e]);
    int row = e >> 6, col = e & 63;
    u16x4 o = { f2bf(f.x), f2bf(f.y), f2bf(f.z), f2bf(f.w) };
    *reinterpret_cast<u16x4*>(&kvs[row * 72 + col]) = o;
  }
  if (tid < 16) {
    float4 f = *reinterpret_cast<const float4*>(&ksum[bh * 64 + tid * 4]);
    ksum_s[tid * 4 + 0] = f.x; ksum_s[tid * 4 + 1] = f.y;
    ksum_s[tid * 4 + 2] = f.z; ksum_s[tid * 4 + 3] = f.w;
  }
  __syncthreads();

  const int lane = tid & 63, w = tid >> 6;
  const int lr = lane & 15, kg = lane >> 4;
  const int s0 = sblk * 64 + w * 16;
  const unsigned short* qrow = q + ((size_t)bh * 4096 + s0 + lr) * 64 + kg * 8;
  u16x8 a0u = *reinterpret_cast<const u16x8*>(qrow);
  u16x8 a1u = *reinterpret_cast<const u16x8*>(qrow + 32);
  bf16x8 a0 = __builtin_bit_cast(bf16x8, a0u);
  bf16x8 a1 = __builtin_bit_cast(bf16x8, a1u);

  float p = 0.f;
#pragma unroll
  for (int j = 0; j < 8; ++j) {
    p += bf2f(a0u[j]) * ksum_s[kg * 8 + j];
    p += bf2f(a1u[j]) * ksum_s[32 + kg * 8 + j];
  }
  p += __shfl_xor(p, 16);
  p += __shfl_xor(p, 32);
  if (kg == 0) norm_s[w * 16 + lr] = p;

  f32x4 accs[4];
#pragma unroll
  for (int jf = 0; jf < 4; ++jf) {
    u16x8 b0u = *reinterpret_cast<const u16x8*>(&kvs[(jf * 16 + lr) * 72 + kg * 8]);
    u16x8 b1u = *reinterpret_cast<const u16x8*>(&kvs[(jf * 16 + lr) * 72 + 32 + kg * 8]);
    f32x4 c = {0.f, 0.f, 0.f, 0.f};
    c = __builtin_amdgcn_mfma_f32_16x16x32_bf16(a0, __builtin_bit_cast(bf16x8, b0u), c, 0, 0, 0);
    c = __builtin_amdgcn_mfma_f32_16x16x32_bf16(a1, __builtin_bit_cast(bf16x8, b1u), c, 0, 0, 0);
    accs[jf] = c;
  }
  float dn[4];
#pragma unroll
  for (int r = 0; r < 4; ++r) dn[r] = norm_s[w * 16 + kg * 4 + r] + 1e-6f;

  unsigned short* ab = attn + (size_t)b * 4096 * 1024 + h * 64;
#pragma unroll
  for (int jf = 0; jf < 4; ++jf)
#pragma unroll
    for (int r = 0; r < 4; ++r) {
      int s = s0 + kg * 4 + r;
      int e2 = jf * 16 + lr;
      ab[(size_t)s * 1024 + e2] = f2bf(accs[jf][r] / dn[r]);
    }
}

extern "C" void kernel_launch(void* const* d_in, const int* in_sizes, int n_in,
                              void* d_out, int out_size, void* d_ws, size_t ws_size,
                              hipStream_t stream) {
  const float* x     = (const float*)d_in[0];
  const float* W_qkv = (const float*)d_in[1];
  const float* W_out = (const float*)d_in[2];
  const float* b_out = (const float*)d_in[3];
  float* out = (float*)d_out;

  unsigned short* xbf   = (unsigned short*)d_ws;            // 16384*1024
  unsigned short* attnb = xbf;                               // alias (xbf dead after gemm_qkv)
  unsigned short* wqkvT = xbf + 16777216;                    // 3072*1024
  unsigned short* woutT = wqkvT + 3145728;                   // 1024*1024
  unsigned short* qb    = woutT + 1048576;                   // 16777216
  unsigned short* kb    = qb + 16777216;
  unsigned short* vb    = kb + 16777216;
  float* kvw            = (float*)(vb + 16777216);           // 262144 f32
  float* ksumw          = kvw + 262144;                      // 4096 f32

  conv_f32_bf16<<<2048, 256, 0, stream>>>(x, xbf, 16777216);
  transpose_f32_bf16<<<dim3(48, 16), 256, 0, stream>>>(W_qkv, wqkvT, 1024, 3072);
  transpose_f32_bf16<<<dim3(16, 16), 256, 0, stream>>>(W_out, woutT, 1024, 1024);
  hipMemsetAsync(kvw, 0, (262144 + 4096) * sizeof(float), stream);
  gemm_qkv<<<768, 512, 0, stream>>>(xbf, wqkvT, qb, kb, vb);
  kv_kernel<<<512, 256, 0, stream>>>(kb, vb, kvw, ksumw);
  num_kernel<<<4096, 256, 0, stream>>>(qb, kvw, ksumw, attnb);
  gemm_out<<<256, 512, 0, stream>>>(attnb, woutT, b_out, out);
}

// Round 10
// 380.732 us; speedup vs baseline: 1.0982x; 1.0982x over previous
//
#include <hip/hip_runtime.h>
#include <hip/hip_bf16.h>

using bf16x8 = __bf16 __attribute__((ext_vector_type(8)));
using f32x4  = float  __attribute__((ext_vector_type(4)));
using u16x8  = unsigned short __attribute__((ext_vector_type(8)));
using u16x4  = unsigned short __attribute__((ext_vector_type(4)));

__device__ __forceinline__ unsigned short f2bf(float f) {
  unsigned u = __builtin_bit_cast(unsigned, f);
  u += 0x7fffu + ((u >> 16) & 1u);
  return (unsigned short)(u >> 16);
}
__device__ __forceinline__ float bf2f(unsigned short h) {
  return __builtin_bit_cast(float, (unsigned)h << 16);
}

__device__ __forceinline__ void gload16(const void* g, void* l) {
  __builtin_amdgcn_global_load_lds(
      (const __attribute__((address_space(1))) void*)g,
      (__attribute__((address_space(3))) void*)l, 16, 0, 0);
}

__device__ __forceinline__ void barrier_raw() {
  asm volatile("" ::: "memory");
  __builtin_amdgcn_s_barrier();
  asm volatile("" ::: "memory");
}
#define VMC4() asm volatile("s_waitcnt vmcnt(4)" ::: "memory")

// ---------------- convert f32 -> bf16 (vectorized) ----------------
__global__ __launch_bounds__(256) void conv_f32_bf16(const float* __restrict__ in,
                                                     unsigned short* __restrict__ out, int n) {
  int stride = gridDim.x * 256 * 4;
  for (int i = (blockIdx.x * 256 + threadIdx.x) * 4; i < n; i += stride) {
    float4 v = *reinterpret_cast<const float4*>(in + i);
    u16x4 o = { f2bf(v.x), f2bf(v.y), f2bf(v.z), f2bf(v.w) };
    *reinterpret_cast<u16x4*>(out + i) = o;
  }
}

// ---------------- transpose + convert: out[c][r] = bf16(in[r][c]) ----------------
__global__ __launch_bounds__(256) void transpose_f32_bf16(const float* __restrict__ in,
                                                          unsigned short* __restrict__ out,
                                                          int R, int C) {
  __shared__ float t[64][65];
  int c0 = blockIdx.x * 64, r0 = blockIdx.y * 64;
  int lx = threadIdx.x & 63, ly = threadIdx.x >> 6;
#pragma unroll
  for (int i = 0; i < 16; ++i) {
    int r = ly * 16 + i;
    t[r][lx] = in[(size_t)(r0 + r) * C + c0 + lx];
  }
  __syncthreads();
#pragma unroll
  for (int i = 0; i < 16; ++i) {
    int c = ly * 16 + i;
    out[(size_t)(c0 + c) * R + r0 + lx] = f2bf(t[lx][c]);
  }
}

// ======== 256x256, BK=64, 8-wave GEMM: A via LDS (dbuf 2x32KB), B DIRECT from
// global (VMEM pipe) — r9 dataflow (numerics verified) trimmed to the 128-VGPR
// budget: FOUR fragment banks (aQ,aR,b0,b1 = 96 regs). Quadrant order
// Q00(b0) -> Q40(b0) -> Q02(b1) -> Q42(b1): b0 dies at Q40, so bL(t+1) reloads
// b0's bank (WAR: issued after Q40, in-order). One barrier per K-step.
// vmcnt ledger (per K-step issue order: b1 x4, A-stage x4, b0next x4):
//   Q02's compiler wait = vmcnt(8) -> drains b1, leaves A+b0next;
//   manual VMC4 before barrier -> drains A(t+1), leaves b0next in flight;
//   next Q00's compiler wait covers b0next (issued a full phase earlier).
__device__ __forceinline__ void gemm256_mainloop(
    const unsigned short* __restrict__ A, const unsigned short* __restrict__ Bt,
    int brow, int bcol, char* lds, f32x4 (&acc)[8][4]) {
  constexpr int NT = 16;  // K = 1024 / 64
  const int tid  = threadIdx.x;
  const int lane = tid & 63;
  const int w    = tid >> 6;
  const int wr   = w >> 2, wc = w & 3;
  const int lr   = lane & 15, kg = lane >> 4;

  // A staging: LDS dest linear (tid*16); global source inverse-swizzled
  const int o0 = tid * 16;
  const int p0 = o0 ^ (((o0 >> 7) & 7) << 4);
  const int off0 = (p0 >> 7) * 2048 + (p0 & 127);
  const int wq = w << 10;

  // swizzled A read addressing: two bases (ck0, ck0^64); buf1 = +32768 imm
  const int xr  = (lr & 7) << 4;
  const int ck0 = (kg * 16) ^ xr;
  const int aoff = wr * 16384 + lr * 128;
  const char* rA00 = lds + aoff + ck0;
  const char* rA01 = lds + aoff + (ck0 ^ 64);

  const char* gA0 = (const char*)(A + (size_t)brow * 1024) + off0;
  const char* gA1 = (const char*)(A + (size_t)(brow + 128) * 1024) + off0;

  // B per-lane row pointers (include kg*16); frag (n,kk,t) at +t*128+kk*64
  const char* gB[4];
#pragma unroll
  for (int n = 0; n < 4; ++n)
    gB[n] = (const char*)(Bt + (size_t)(bcol + wc * 64 + n * 16 + lr) * 1024) + kg * 16;

  auto STG = [&](const char*& g, int region) {
    gload16(g, lds + region + wq);
    gload16(g + 131072, lds + region + 8192 + wq);  // rows 64-127 (+64*2048)
    g += 128;                                        // next K-step
  };

  bf16x8 aQ[4][2], aR[4][2], b0[2][2], b1[2][2];

  auto READ_A = [&](bf16x8 (&dst)[4][2], int bufo, int mb) {
#pragma unroll
    for (int m = 0; m < 4; ++m) {
      dst[m][0] = __builtin_bit_cast(bf16x8, *(const u16x8*)(rA00 + bufo + (mb + m) * 2048));
      dst[m][1] = __builtin_bit_cast(bf16x8, *(const u16x8*)(rA01 + bufo + (mb + m) * 2048));
    }
  };
  auto GLOAD_B = [&](bf16x8 (&dst)[2][2], int nb, int tbytes) {
#pragma unroll
    for (int n = 0; n < 2; ++n) {
      dst[n][0] = __builtin_bit_cast(bf16x8, *(const u16x8*)(gB[nb + n] + tbytes));
      dst[n][1] = __builtin_bit_cast(bf16x8, *(const u16x8*)(gB[nb + n] + tbytes + 64));
    }
  };
  auto MFMA_Q = [&](int mb, int nb, bf16x8 (&Af)[4][2], bf16x8 (&Bf)[2][2]) {
    __builtin_amdgcn_s_setprio(1);
#pragma unroll
    for (int kk = 0; kk < 2; ++kk)
#pragma unroll
      for (int m = 0; m < 4; ++m)
#pragma unroll
        for (int n = 0; n < 2; ++n)
          acc[mb + m][nb + n] =
              __builtin_amdgcn_mfma_f32_16x16x32_bf16(Af[m][kk], Bf[n][kk], acc[mb + m][nb + n], 0, 0, 0);
    __builtin_amdgcn_s_setprio(0);
  };

  // ---- prologue: A(0)->buf0, bL(0) from global ----
  STG(gA0, 0); STG(gA1, 16384);
  GLOAD_B(b0, 0, 0);
  VMC4();          // drain A(0)'s 4 loads; b0 awaited by compiler at Q00
  barrier_raw();
  READ_A(aQ, 0, 0);

  for (int t = 0; t < NT; t += 2) {
    // ================= even iter: cur=buf0, nxt=buf1 =================
    GLOAD_B(b1, 2, t << 7);                              // bH(t)
    if (t + 1 < NT) { STG(gA0, 32768); STG(gA1, 49152); }  // A(t+1)->buf1
    READ_A(aR, 0, 4);
    MFMA_Q(0, 0, aQ, b0);                                // Q00
    MFMA_Q(4, 0, aR, b0);                                // Q40 (b0 dies)
    if (t + 1 < NT) GLOAD_B(b0, 0, (t + 1) << 7);        // bL(t+1) -> b0 bank
    MFMA_Q(0, 2, aQ, b1);                                // Q02 (waits b1)
    if (t + 1 < NT) VMC4();                              // drain A(t+1)
    barrier_raw();
    if (t + 1 < NT) READ_A(aQ, 32768, 0);                // aQ(t+1) from buf1
    MFMA_Q(4, 2, aR, b1);                                // Q42 overlaps reads

    // ================= odd iter t+1: cur=buf1, nxt=buf0 =================
    if (t + 1 < NT) {
      GLOAD_B(b1, 2, (t + 1) << 7);
      if (t + 2 < NT) { STG(gA0, 0); STG(gA1, 16384); }  // A(t+2)->buf0
      READ_A(aR, 32768, 4);
      MFMA_Q(0, 0, aQ, b0);
      MFMA_Q(4, 0, aR, b0);
      if (t + 2 < NT) GLOAD_B(b0, 0, (t + 2) << 7);
      MFMA_Q(0, 2, aQ, b1);
      if (t + 2 < NT) VMC4();
      barrier_raw();
      if (t + 2 < NT) READ_A(aQ, 0, 0);
      MFMA_Q(4, 2, aR, b1);
    }
  }
}

// ---------------- GEMM1: qkv = x @ W_qkv, epilogue elu+1 on q,k; scatter (B,H,N,D) ----------------
__global__ __launch_bounds__(512, 2) void gemm_qkv(
    const unsigned short* __restrict__ xbf, const unsigned short* __restrict__ wt,
    unsigned short* __restrict__ q, unsigned short* __restrict__ k, unsigned short* __restrict__ v) {
  __shared__ __align__(16) char lds[65536];
  f32x4 acc[8][4] = {};
  // L2-patch grid: XCD r owns tm stripe [8r,8r+8), tn-major within the stripe.
  const int bid = blockIdx.x;                    // 768 = 8 XCD x 8 tm x 12 tn
  const int r = bid & 7, i = bid >> 3;
  const int tm = r * 8 + (i & 7);
  const int tn = i >> 3;
  const int brow = tm * 256, bcol = tn * 256;
  gemm256_mainloop(xbf, wt, brow, bcol, lds, acc);

  const int lane = threadIdx.x & 63, w = threadIdx.x >> 6;
  const int wr = w >> 2, wc = w & 3;
  const int lr = lane & 15, kg = lane >> 4;
#pragma unroll
  for (int m = 0; m < 8; ++m)
#pragma unroll
    for (int n = 0; n < 4; ++n)
#pragma unroll
      for (int rr = 0; rr < 4; ++rr) {
        int grow = brow + wr * 128 + m * 16 + kg * 4 + rr;
        int gcol = bcol + wc * 64 + n * 16 + lr;
        float val = acc[m][n][rr];
        int tt = gcol >> 10;
        int h = (gcol >> 6) & 15;
        int d = gcol & 63;
        int b = grow >> 12, s = grow & 4095;
        size_t idx = ((size_t)(b * 16 + h) * 4096 + s) * 64 + d;
        if (tt < 2) {
          val = val > 0.f ? val + 1.f : __expf(val);  // elu(x)+1
          (tt == 0 ? q : k)[idx] = f2bf(val);
        } else {
          v[idx] = f2bf(val);
        }
      }
}

// ---------------- GEMM2: out = attn @ W_out + b ----------------
__global__ __launch_bounds__(512, 2) void gemm_out(
    const unsigned short* __restrict__ attn, const unsigned short* __restrict__ wt,
    const float* __restrict__ bias, float* __restrict__ out) {
  __shared__ __align__(16) char lds[65536];
  f32x4 acc[8][4] = {};
  const int bid = blockIdx.x;                    // 256 = 8 XCD x 8 tm x 4 tn
  const int r = bid & 7, i = bid >> 3;
  const int tm = r * 8 + (i & 7);
  const int tn = i >> 3;
  const int brow = tm * 256, bcol = tn * 256;
  gemm256_mainloop(attn, wt, brow, bcol, lds, acc);

  const int lane = threadIdx.x & 63, w = threadIdx.x >> 6;
  const int wr = w >> 2, wc = w & 3;
  const int lr = lane & 15, kg = lane >> 4;
#pragma unroll
  for (int m = 0; m < 8; ++m)
#pragma unroll
    for (int n = 0; n < 4; ++n)
#pragma unroll
      for (int rr = 0; rr < 4; ++rr) {
        int grow = brow + wr * 128 + m * 16 + kg * 4 + rr;
        int gcol = bcol + wc * 64 + n * 16 + lr;
        out[(size_t)grow * 1024 + gcol] = acc[m][n][rr] + bias[gcol];
      }
}

// ---------------- kv[d][e] = sum_n k[n][d] v[n][e]  (stored [e][d]); ksum[d] ----------------
__global__ __launch_bounds__(256) void kv_kernel(
    const unsigned short* __restrict__ k, const unsigned short* __restrict__ v,
    float* __restrict__ kv, float* __restrict__ ksum) {
  const int bid = blockIdx.x;             // B*H*8 = 512
  const int bh = bid >> 3, chunk = bid & 7;
  const unsigned short* kb = k + (size_t)bh * 4096 * 64 + chunk * 512 * 64;
  const unsigned short* vb = v + (size_t)bh * 4096 * 64 + chunk * 512 * 64;
  __shared__ unsigned short ks[64 * 64];
  __shared__ unsigned short vs[64 * 64];
  const int tid = threadIdx.x;
  const int ty = tid >> 4, tx = tid & 15;
  float acc[4][4] = {};
  float ksacc[4] = {};
  for (int t = 0; t < 8; ++t) {
    const unsigned short* ksrc = kb + t * 4096;
    const unsigned short* vsrc = vb + t * 4096;
    *reinterpret_cast<u16x8*>(&ks[tid * 8])        = *reinterpret_cast<const u16x8*>(ksrc + tid * 8);
    *reinterpret_cast<u16x8*>(&ks[2048 + tid * 8]) = *reinterpret_cast<const u16x8*>(ksrc + 2048 + tid * 8);
    *reinterpret_cast<u16x8*>(&vs[tid * 8])        = *reinterpret_cast<const u16x8*>(vsrc + tid * 8);
    *reinterpret_cast<u16x8*>(&vs[2048 + tid * 8]) = *reinterpret_cast<const u16x8*>(vsrc + 2048 + tid * 8);
    __syncthreads();
#pragma unroll 4
    for (int nn = 0; nn < 64; ++nn) {
      u16x4 ku = *reinterpret_cast<const u16x4*>(&ks[nn * 64 + ty * 4]);
      u16x4 vu = *reinterpret_cast<const u16x4*>(&vs[nn * 64 + tx * 4]);
      float kd[4], ve[4];
#pragma unroll
      for (int i = 0; i < 4; ++i) { kd[i] = bf2f(ku[i]); ve[i] = bf2f(vu[i]); }
#pragma unroll
      for (int i = 0; i < 4; ++i) ksacc[i] += kd[i];
#pragma unroll
      for (int i = 0; i < 4; ++i)
#pragma unroll
        for (int j = 0; j < 4; ++j) acc[i][j] += kd[i] * ve[j];
    }
    __syncthreads();
  }
  float* kvb = kv + (size_t)bh * 4096;
#pragma unroll
  for (int i = 0; i < 4; ++i)
#pragma unroll
    for (int j = 0; j < 4; ++j)
      atomicAdd(&kvb[(tx * 4 + j) * 64 + ty * 4 + i], acc[i][j]);  // [e][d]
  if (tx == 0) {
#pragma unroll
    for (int i = 0; i < 4; ++i) atomicAdd(&ksum[bh * 64 + ty * 4 + i], ksacc[i]);
  }
}

// ---------------- num = q @ kv ; attn = num / (q.ksum + 1e-6) ----------------
__global__ __launch_bounds__(256) void num_kernel(
    const unsigned short* __restrict__ q, const float* __restrict__ kv,
    const float* __restrict__ ksum, unsigned short* __restrict__ attn) {
  const int bid = blockIdx.x;              // B*H*64 = 4096
  const int bh = bid >> 6, sblk = bid & 63;
  const int b = bh >> 4, h = bh & 15;
  __shared__ unsigned short kvs[64 * 72];
  __shared__ float ksum_s[64];
  __shared__ float norm_s[64];
  const int tid = threadIdx.x;
  const float* kvb = kv + (size_t)bh * 4096;
#pragma unroll
  for (int r = 0; r < 4; ++r) {
    int e = r * 1024 + tid * 4;
    float4 f = *reinterpret_cast<const float4*>(&kvb[e]);
    int row = e >> 6, col = e & 63;
    u16x4 o = { f2bf(f.x), f2bf(f.y), f2bf(f.z), f2bf(f.w) };
    *reinterpret_cast<u16x4*>(&kvs[row * 72 + col]) = o;
  }
  if (tid < 16) {
    float4 f = *reinterpret_cast<const float4*>(&ksum[bh * 64 + tid * 4]);
    ksum_s[tid * 4 + 0] = f.x; ksum_s[tid * 4 + 1] = f.y;
    ksum_s[tid * 4 + 2] = f.z; ksum_s[tid * 4 + 3] = f.w;
  }
  __syncthreads();

  const int lane = tid & 63, w = tid >> 6;
  const int lr = lane & 15, kg = lane >> 4;
  const int s0 = sblk * 64 + w * 16;
  const unsigned short* qrow = q + ((size_t)bh * 4096 + s0 + lr) * 64 + kg * 8;
  u16x8 a0u = *reinterpret_cast<const u16x8*>(qrow);
  u16x8 a1u = *reinterpret_cast<const u16x8*>(qrow + 32);
  bf16x8 a0 = __builtin_bit_cast(bf16x8, a0u);
  bf16x8 a1 = __builtin_bit_cast(bf16x8, a1u);

  float p = 0.f;
#pragma unroll
  for (int j = 0; j < 8; ++j) {
    p += bf2f(a0u[j]) * ksum_s[kg * 8 + j];
    p += bf2f(a1u[j]) * ksum_s[32 + kg * 8 + j];
  }
  p += __shfl_xor(p, 16);
  p += __shfl_xor(p, 32);
  if (kg == 0) norm_s[w * 16 + lr] = p;

  f32x4 accs[4];
#pragma unroll
  for (int jf = 0; jf < 4; ++jf) {
    u16x8 b0u = *reinterpret_cast<const u16x8*>(&kvs[(jf * 16 + lr) * 72 + kg * 8]);
    u16x8 b1u = *reinterpret_cast<const u16x8*>(&kvs[(jf * 16 + lr) * 72 + 32 + kg * 8]);
    f32x4 c = {0.f, 0.f, 0.f, 0.f};
    c = __builtin_amdgcn_mfma_f32_16x16x32_bf16(a0, __builtin_bit_cast(bf16x8, b0u), c, 0, 0, 0);
    c = __builtin_amdgcn_mfma_f32_16x16x32_bf16(a1, __builtin_bit_cast(bf16x8, b1u), c, 0, 0, 0);
    accs[jf] = c;
  }
  float dn[4];
#pragma unroll
  for (int r = 0; r < 4; ++r) dn[r] = norm_s[w * 16 + kg * 4 + r] + 1e-6f;

  unsigned short* ab = attn + (size_t)b * 4096 * 1024 + h * 64;
#pragma unroll
  for (int jf = 0; jf < 4; ++jf)
#pragma unroll
    for (int r = 0; r < 4; ++r) {
      int s = s0 + kg * 4 + r;
      int e2 = jf * 16 + lr;
      ab[(size_t)s * 1024 + e2] = f2bf(accs[jf][r] / dn[r]);
    }
}

extern "C" void kernel_launch(void* const* d_in, const int* in_sizes, int n_in,
                              void* d_out, int out_size, void* d_ws, size_t ws_size,
                              hipStream_t stream) {
  const float* x     = (const float*)d_in[0];
  const float* W_qkv = (const float*)d_in[1];
  const float* W_out = (const float*)d_in[2];
  const float* b_out = (const float*)d_in[3];
  float* out = (float*)d_out;

  unsigned short* xbf   = (unsigned short*)d_ws;            // 16384*1024
  unsigned short* attnb = xbf;                               // alias (xbf dead after gemm_qkv)
  unsigned short* wqkvT = xbf + 16777216;                    // 3072*1024
  unsigned short* woutT = wqkvT + 3145728;                   // 1024*1024
  unsigned short* qb    = woutT + 1048576;                   // 16777216
  unsigned short* kb    = qb + 16777216;
  unsigned short* vb    = kb + 16777216;
  float* kvw            = (float*)(vb + 16777216);           // 262144 f32
  float* ksumw          = kvw + 262144;                      // 4096 f32

  conv_f32_bf16<<<2048, 256, 0, stream>>>(x, xbf, 16777216);
  transpose_f32_bf16<<<dim3(48, 16), 256, 0, stream>>>(W_qkv, wqkvT, 1024, 3072);
  transpose_f32_bf16<<<dim3(16, 16), 256, 0, stream>>>(W_out, woutT, 1024, 1024);
  hipMemsetAsync(kvw, 0, (262144 + 4096) * sizeof(float), stream);
  gemm_qkv<<<768, 512, 0, stream>>>(xbf, wqkvT, qb, kb, vb);
  kv_kernel<<<512, 256, 0, stream>>>(kb, vb, kvw, ksumw);
  num_kernel<<<4096, 256, 0, stream>>>(qb, kvw, ksumw, attnb);
  gemm_out<<<256, 512, 0, stream>>>(attnb, woutT, b_out, out);
}

// Round 11
// 301.756 us; speedup vs baseline: 1.3856x; 1.2617x over previous
//
#include <hip/hip_runtime.h>
#include <hip/hip_bf16.h>

using bf16x8 = __bf16 __attribute__((ext_vector_type(8)));
using f32x4  = float  __attribute__((ext_vector_type(4)));
using u16x8  = unsigned short __attribute__((ext_vector_type(8)));
using u16x4  = unsigned short __attribute__((ext_vector_type(4)));

__device__ __forceinline__ unsigned short f2bf(float f) {
  unsigned u = __builtin_bit_cast(unsigned, f);
  u += 0x7fffu + ((u >> 16) & 1u);
  return (unsigned short)(u >> 16);
}
__device__ __forceinline__ float bf2f(unsigned short h) {
  return __builtin_bit_cast(float, (unsigned)h << 16);
}

__device__ __forceinline__ void gload16(const void* g, void* l) {
  __builtin_amdgcn_global_load_lds(
      (const __attribute__((address_space(1))) void*)g,
      (__attribute__((address_space(3))) void*)l, 16, 0, 0);
}

__device__ __forceinline__ void barrier_raw() {
  asm volatile("" ::: "memory");
  __builtin_amdgcn_s_barrier();
  asm volatile("" ::: "memory");
}
#define VMC4() asm volatile("s_waitcnt vmcnt(4)" ::: "memory")
#define VMC0() asm volatile("s_waitcnt vmcnt(0)" ::: "memory")

// ---------------- convert f32 -> bf16 (vectorized) ----------------
__global__ __launch_bounds__(256) void conv_f32_bf16(const float* __restrict__ in,
                                                     unsigned short* __restrict__ out, int n) {
  int stride = gridDim.x * 256 * 4;
  for (int i = (blockIdx.x * 256 + threadIdx.x) * 4; i < n; i += stride) {
    float4 v = *reinterpret_cast<const float4*>(in + i);
    u16x4 o = { f2bf(v.x), f2bf(v.y), f2bf(v.z), f2bf(v.w) };
    *reinterpret_cast<u16x4*>(out + i) = o;
  }
}

// ---------------- transpose + convert: out[c][r] = bf16(in[r][c]) ----------------
__global__ __launch_bounds__(256) void transpose_f32_bf16(const float* __restrict__ in,
                                                          unsigned short* __restrict__ out,
                                                          int R, int C) {
  __shared__ float t[64][65];
  int c0 = blockIdx.x * 64, r0 = blockIdx.y * 64;
  int lx = threadIdx.x & 63, ly = threadIdx.x >> 6;
#pragma unroll
  for (int i = 0; i < 16; ++i) {
    int r = ly * 16 + i;
    t[r][lx] = in[(size_t)(r0 + r) * C + c0 + lx];
  }
  __syncthreads();
#pragma unroll
  for (int i = 0; i < 16; ++i) {
    int c = ly * 16 + i;
    out[(size_t)(c0 + c) * R + r0 + lx] = f2bf(t[lx][c]);
  }
}

// ======== 256x256, BK=64, 8-wave GEMM mainloop with WAVE-PARITY ANTI-PHASE ========
// r5 dataflow (A+B via LDS, dbuf, XOR-swizzle, verified) with ONE change: even
// waves execute quadrants Q00->Q02->Q42->Q40, odd waves Q42->Q40->Q00->Q02,
// over the SAME four fragment banks (aQ,aR,bL,bH = 96 regs, r4's proven-fit
// budget). At any instant half the waves per SIMD issue MFMA while the other
// half issue ds_reads -> matrix and LDS pipes overlap instead of serializing
// (the measured 31% lockstep ceiling of r5/r7). Barriers and staging uniform
// across parities. vmcnt ledger at VMC4: outstanding = B(t+1)[4] + A(t+1)[4]
// + B(t+2)[4] = 12 -> drains B(t+1),A(t+1), leaves B(t+2) in flight.
__device__ __forceinline__ void gemm256_mainloop(
    const unsigned short* __restrict__ A, const unsigned short* __restrict__ Bt,
    int brow, int bcol, char* lds, f32x4 (&acc)[8][4]) {
  constexpr int NT = 16;  // K = 1024 / 64
  const int tid  = threadIdx.x;
  const int lane = tid & 63;
  const int w    = tid >> 6;
  const int wr   = w >> 2, wc = w & 3;
  const int lr   = lane & 15, kg = lane >> 4;
  const bool wodd = (w & 1);

  // staging: LDS dest linear (tid*16); global source inverse-swizzled
  const int o0 = tid * 16;
  const int p0 = o0 ^ (((o0 >> 7) & 7) << 4);
  const int off0 = (p0 >> 7) * 2048 + (p0 & 127);
  const int wq = w << 10;

  // swizzled read addressing: second k-half = ck0 ^ 64 (row-XOR involution)
  const int xr  = (lr & 7) << 4;
  const int ck0 = (kg * 16) ^ xr;
  const int aoff = wr * 16384 + lr * 128;
  const int boff = 32768 + (wc >> 1) * 16384 + (wc & 1) * 8192 + lr * 128;

  const char* rA0 = lds + aoff + ck0;
  const char* rA1 = lds + aoff + (ck0 ^ 64);
  const char* rB0 = lds + boff + ck0;
  const char* rB1 = lds + boff + (ck0 ^ 64);

  const char* gA0 = (const char*)(A  + (size_t)brow * 1024) + off0;
  const char* gA1 = (const char*)(A  + (size_t)(brow + 128) * 1024) + off0;
  const char* gB0 = (const char*)(Bt + (size_t)bcol * 1024) + off0;
  const char* gB1 = (const char*)(Bt + (size_t)(bcol + 128) * 1024) + off0;

  auto STG = [&](const char*& g, int region) {
    gload16(g, lds + region + wq);
    gload16(g + 131072, lds + region + 8192 + wq);  // rows 64-127 (+64*2048)
    g += 128;                                        // next K-step
  };

  bf16x8 aQ[4][2], aR[4][2], bL[2][2], bH[2][2];

  auto READ_A = [&](bf16x8 (&dst)[4][2], int bufo, int mb) {
#pragma unroll
    for (int m = 0; m < 4; ++m) {
      dst[m][0] = __builtin_bit_cast(bf16x8, *(const u16x8*)(rA0 + bufo + (mb + m) * 2048));
      dst[m][1] = __builtin_bit_cast(bf16x8, *(const u16x8*)(rA1 + bufo + (mb + m) * 2048));
    }
  };
  auto READ_B = [&](bf16x8 (&dst)[2][2], int bufo, int nb) {
#pragma unroll
    for (int n = 0; n < 2; ++n) {
      dst[n][0] = __builtin_bit_cast(bf16x8, *(const u16x8*)(rB0 + bufo + (nb + n) * 2048));
      dst[n][1] = __builtin_bit_cast(bf16x8, *(const u16x8*)(rB1 + bufo + (nb + n) * 2048));
    }
  };
  auto MFMA_Q = [&](int mb, int nb, bf16x8 (&Af)[4][2], bf16x8 (&Bf)[2][2]) {
    __builtin_amdgcn_s_setprio(1);
#pragma unroll
    for (int kk = 0; kk < 2; ++kk)
#pragma unroll
      for (int m = 0; m < 4; ++m)
#pragma unroll
        for (int n = 0; n < 2; ++n)
          acc[mb + m][nb + n] =
              __builtin_amdgcn_mfma_f32_16x16x32_bf16(Af[m][kk], Bf[n][kk], acc[mb + m][nb + n], 0, 0, 0);
    __builtin_amdgcn_s_setprio(0);
  };

  auto KBODY = [&](int t, int bufo, int nbufo) {
    // ---- C1: first operand pair + A(t+1) stage + first quadrant ----
    if (!wodd) { READ_A(aQ, bufo, 0); READ_B(bL, bufo, 0); }
    else       { READ_A(aR, bufo, 4); READ_B(bH, bufo, 2); }
    if (t + 1 < NT) { STG(gA0, nbufo); STG(gA1, nbufo + 16384); }
    if (!wodd) MFMA_Q(0, 0, aQ, bL); else MFMA_Q(4, 2, aR, bH);
    // ---- C2: second B + second quadrant (B(t) reads complete here) ----
    if (!wodd) { READ_B(bH, bufo, 2); MFMA_Q(0, 2, aQ, bH); }
    else       { READ_B(bL, bufo, 0); MFMA_Q(4, 0, aR, bL); }
    // ---- C3: second A + third quadrant (A(t) reads complete here) ----
    if (!wodd) { READ_A(aR, bufo, 4); MFMA_Q(4, 2, aR, bH); }
    else       { READ_A(aQ, bufo, 0); MFMA_Q(0, 0, aQ, bL); }
    barrier_raw();   // all reads of buf(t) done across waves
    // ---- stage B(t+2) -> bufo's B region; counted drain ----
    if (t + 2 < NT) {
      STG(gB0, bufo + 32768); STG(gB1, bufo + 49152);
      VMC4();                        // drains B(t+1)+A(t+1), keeps B(t+2)
    } else if (t + 1 < NT) {
      VMC0();                        // tail: drain A(t+1)/B(t+1)
    }
    barrier_raw();                   // buf(t+1) visible to all waves
    // ---- C4: register-only quadrant, overlaps next step's reads ----
    if (!wodd) MFMA_Q(4, 0, aR, bL); else MFMA_Q(0, 2, aQ, bH);
  };

  // ---- prologue: A(0),B(0) -> buf0; B(1) -> buf1 (left in flight) ----
  STG(gA0, 0); STG(gA1, 16384);
  STG(gB0, 32768); STG(gB1, 49152);
  STG(gB0, 65536 + 32768); STG(gB1, 65536 + 49152);
  VMC4();          // drain A(0)+B(0) (8 oldest of 12), keep B(1) in flight
  barrier_raw();

  for (int t = 0; t < NT; t += 2) {
    KBODY(t,     0,     65536);   // cur buf0, A(t+1) -> buf1
    KBODY(t + 1, 65536, 0);       // cur buf1, A(t+2) -> buf0
  }
}

// ---------------- GEMM1: qkv = x @ W_qkv, epilogue elu+1 on q,k; scatter (B,H,N,D) ----------------
__global__ __launch_bounds__(512, 2) void gemm_qkv(
    const unsigned short* __restrict__ xbf, const unsigned short* __restrict__ wt,
    unsigned short* __restrict__ q, unsigned short* __restrict__ k, unsigned short* __restrict__ v) {
  __shared__ __align__(16) char lds[131072];
  f32x4 acc[8][4] = {};
  // L2-patch grid: XCD r owns tm stripe [8r,8r+8), tn-major within the stripe.
  const int bid = blockIdx.x;                    // 768 = 8 XCD x 8 tm x 12 tn
  const int r = bid & 7, i = bid >> 3;
  const int tm = r * 8 + (i & 7);
  const int tn = i >> 3;
  const int brow = tm * 256, bcol = tn * 256;
  gemm256_mainloop(xbf, wt, brow, bcol, lds, acc);

  const int lane = threadIdx.x & 63, w = threadIdx.x >> 6;
  const int wr = w >> 2, wc = w & 3;
  const int lr = lane & 15, kg = lane >> 4;
#pragma unroll
  for (int m = 0; m < 8; ++m)
#pragma unroll
    for (int n = 0; n < 4; ++n)
#pragma unroll
      for (int rr = 0; rr < 4; ++rr) {
        int grow = brow + wr * 128 + m * 16 + kg * 4 + rr;
        int gcol = bcol + wc * 64 + n * 16 + lr;
        float val = acc[m][n][rr];
        int tt = gcol >> 10;
        int h = (gcol >> 6) & 15;
        int d = gcol & 63;
        int b = grow >> 12, s = grow & 4095;
        size_t idx = ((size_t)(b * 16 + h) * 4096 + s) * 64 + d;
        if (tt < 2) {
          val = val > 0.f ? val + 1.f : __expf(val);  // elu(x)+1
          (tt == 0 ? q : k)[idx] = f2bf(val);
        } else {
          v[idx] = f2bf(val);
        }
      }
}

// ---------------- GEMM2: out = attn @ W_out + b ----------------
__global__ __launch_bounds__(512, 2) void gemm_out(
    const unsigned short* __restrict__ attn, const unsigned short* __restrict__ wt,
    const float* __restrict__ bias, float* __restrict__ out) {
  __shared__ __align__(16) char lds[131072];
  f32x4 acc[8][4] = {};
  const int bid = blockIdx.x;                    // 256 = 8 XCD x 8 tm x 4 tn
  const int r = bid & 7, i = bid >> 3;
  const int tm = r * 8 + (i & 7);
  const int tn = i >> 3;
  const int brow = tm * 256, bcol = tn * 256;
  gemm256_mainloop(attn, wt, brow, bcol, lds, acc);

  const int lane = threadIdx.x & 63, w = threadIdx.x >> 6;
  const int wr = w >> 2, wc = w & 3;
  const int lr = lane & 15, kg = lane >> 4;
#pragma unroll
  for (int m = 0; m < 8; ++m)
#pragma unroll
    for (int n = 0; n < 4; ++n)
#pragma unroll
      for (int rr = 0; rr < 4; ++rr) {
        int grow = brow + wr * 128 + m * 16 + kg * 4 + rr;
        int gcol = bcol + wc * 64 + n * 16 + lr;
        out[(size_t)grow * 1024 + gcol] = acc[m][n][rr] + bias[gcol];
      }
}

// ---------------- kv[d][e] = sum_n k[n][d] v[n][e]  (stored [e][d]); ksum[d] ----------------
__global__ __launch_bounds__(256) void kv_kernel(
    const unsigned short* __restrict__ k, const unsigned short* __restrict__ v,
    float* __restrict__ kv, float* __restrict__ ksum) {
  const int bid = blockIdx.x;             // B*H*8 = 512
  const int bh = bid >> 3, chunk = bid & 7;
  const unsigned short* kb = k + (size_t)bh * 4096 * 64 + chunk * 512 * 64;
  const unsigned short* vb = v + (size_t)bh * 4096 * 64 + chunk * 512 * 64;
  __shared__ unsigned short ks[64 * 64];
  __shared__ unsigned short vs[64 * 64];
  const int tid = threadIdx.x;
  const int ty = tid >> 4, tx = tid & 15;
  float acc[4][4] = {};
  float ksacc[4] = {};
  for (int t = 0; t < 8; ++t) {
    const unsigned short* ksrc = kb + t * 4096;
    const unsigned short* vsrc = vb + t * 4096;
    *reinterpret_cast<u16x8*>(&ks[tid * 8])        = *reinterpret_cast<const u16x8*>(ksrc + tid * 8);
    *reinterpret_cast<u16x8*>(&ks[2048 + tid * 8]) = *reinterpret_cast<const u16x8*>(ksrc + 2048 + tid * 8);
    *reinterpret_cast<u16x8*>(&vs[tid * 8])        = *reinterpret_cast<const u16x8*>(vsrc + tid * 8);
    *reinterpret_cast<u16x8*>(&vs[2048 + tid * 8]) = *reinterpret_cast<const u16x8*>(vsrc + 2048 + tid * 8);
    __syncthreads();
#pragma unroll 4
    for (int nn = 0; nn < 64; ++nn) {
      u16x4 ku = *reinterpret_cast<const u16x4*>(&ks[nn * 64 + ty * 4]);
      u16x4 vu = *reinterpret_cast<const u16x4*>(&vs[nn * 64 + tx * 4]);
      float kd[4], ve[4];
#pragma unroll
      for (int i = 0; i < 4; ++i) { kd[i] = bf2f(ku[i]); ve[i] = bf2f(vu[i]); }
#pragma unroll
      for (int i = 0; i < 4; ++i) ksacc[i] += kd[i];
#pragma unroll
      for (int i = 0; i < 4; ++i)
#pragma unroll
        for (int j = 0; j < 4; ++j) acc[i][j] += kd[i] * ve[j];
    }
    __syncthreads();
  }
  float* kvb = kv + (size_t)bh * 4096;
#pragma unroll
  for (int i = 0; i < 4; ++i)
#pragma unroll
    for (int j = 0; j < 4; ++j)
      atomicAdd(&kvb[(tx * 4 + j) * 64 + ty * 4 + i], acc[i][j]);  // [e][d]
  if (tx == 0) {
#pragma unroll
    for (int i = 0; i < 4; ++i) atomicAdd(&ksum[bh * 64 + ty * 4 + i], ksacc[i]);
  }
}

// ---------------- num = q @ kv ; attn = num / (q.ksum + 1e-6) ----------------
__global__ __launch_bounds__(256) void num_kernel(
    const unsigned short* __restrict__ q, const float* __restrict__ kv,
    const float* __restrict__ ksum, unsigned short* __restrict__ attn) {
  const int bid = blockIdx.x;              // B*H*64 = 4096
  const int bh = bid >> 6, sblk = bid & 63;
  const int b = bh >> 4, h = bh & 15;
  __shared__ unsigned short kvs[64 * 72];
  __shared__ float ksum_s[64];
  __shared__ float norm_s[64];
  const int tid = threadIdx.x;
  const float* kvb = kv + (size_t)bh * 4096;
#pragma unroll
  for (int r = 0; r < 4; ++r) {
    int e = r * 1024 + tid * 4;
    float4 f = *reinterpret_cast<const float4*>(&kvb[e]);
    int row = e >> 6, col = e & 63;
    u16x4 o = { f2bf(f.x), f2bf(f.y), f2bf(f.z), f2bf(f.w) };
    *reinterpret_cast<u16x4*>(&kvs[row * 72 + col]) = o;
  }
  if (tid < 16) {
    float4 f = *reinterpret_cast<const float4*>(&ksum[bh * 64 + tid * 4]);
    ksum_s[tid * 4 + 0] = f.x; ksum_s[tid * 4 + 1] = f.y;
    ksum_s[tid * 4 + 2] = f.z; ksum_s[tid * 4 + 3] = f.w;
  }
  __syncthreads();

  const int lane = tid & 63, w = tid >> 6;
  const int lr = lane & 15, kg = lane >> 4;
  const int s0 = sblk * 64 + w * 16;
  const unsigned short* qrow = q + ((size_t)bh * 4096 + s0 + lr) * 64 + kg * 8;
  u16x8 a0u = *reinterpret_cast<const u16x8*>(qrow);
  u16x8 a1u = *reinterpret_cast<const u16x8*>(qrow + 32);
  bf16x8 a0 = __builtin_bit_cast(bf16x8, a0u);
  bf16x8 a1 = __builtin_bit_cast(bf16x8, a1u);

  float p = 0.f;
#pragma unroll
  for (int j = 0; j < 8; ++j) {
    p += bf2f(a0u[j]) * ksum_s[kg * 8 + j];
    p += bf2f(a1u[j]) * ksum_s[32 + kg * 8 + j];
  }
  p += __shfl_xor(p, 16);
  p += __shfl_xor(p, 32);
  if (kg == 0) norm_s[w * 16 + lr] = p;

  f32x4 accs[4];
#pragma unroll
  for (int jf = 0; jf < 4; ++jf) {
    u16x8 b0u = *reinterpret_cast<const u16x8*>(&kvs[(jf * 16 + lr) * 72 + kg * 8]);
    u16x8 b1u = *reinterpret_cast<const u16x8*>(&kvs[(jf * 16 + lr) * 72 + 32 + kg * 8]);
    f32x4 c = {0.f, 0.f, 0.f, 0.f};
    c = __builtin_amdgcn_mfma_f32_16x16x32_bf16(a0, __builtin_bit_cast(bf16x8, b0u), c, 0, 0, 0);
    c = __builtin_amdgcn_mfma_f32_16x16x32_bf16(a1, __builtin_bit_cast(bf16x8, b1u), c, 0, 0, 0);
    accs[jf] = c;
  }
  float dn[4];
#pragma unroll
  for (int r = 0; r < 4; ++r) dn[r] = norm_s[w * 16 + kg * 4 + r] + 1e-6f;

  unsigned short* ab = attn + (size_t)b * 4096 * 1024 + h * 64;
#pragma unroll
  for (int jf = 0; jf < 4; ++jf)
#pragma unroll
    for (int r = 0; r < 4; ++r) {
      int s = s0 + kg * 4 + r;
      int e2 = jf * 16 + lr;
      ab[(size_t)s * 1024 + e2] = f2bf(accs[jf][r] / dn[r]);
    }
}

extern "C" void kernel_launch(void* const* d_in, const int* in_sizes, int n_in,
                              void* d_out, int out_size, void* d_ws, size_t ws_size,
                              hipStream_t stream) {
  const float* x     = (const float*)d_in[0];
  const float* W_qkv = (const float*)d_in[1];
  const float* W_out = (const float*)d_in[2];
  const float* b_out = (const float*)d_in[3];
  float* out = (float*)d_out;

  unsigned short* xbf   = (unsigned short*)d_ws;            // 16384*1024
  unsigned short* attnb = xbf;                               // alias (xbf dead after gemm_qkv)
  unsigned short* wqkvT = xbf + 16777216;                    // 3072*1024
  unsigned short* woutT = wqkvT + 3145728;                   // 1024*1024
  unsigned short* qb    = woutT + 1048576;                   // 16777216
  unsigned short* kb    = qb + 16777216;
  unsigned short* vb    = kb + 16777216;
  float* kvw            = (float*)(vb + 16777216);           // 262144 f32
  float* ksumw          = kvw + 262144;                      // 4096 f32

  conv_f32_bf16<<<2048, 256, 0, stream>>>(x, xbf, 16777216);
  transpose_f32_bf16<<<dim3(48, 16), 256, 0, stream>>>(W_qkv, wqkvT, 1024, 3072);
  transpose_f32_bf16<<<dim3(16, 16), 256, 0, stream>>>(W_out, woutT, 1024, 1024);
  hipMemsetAsync(kvw, 0, (262144 + 4096) * sizeof(float), stream);
  gemm_qkv<<<768, 512, 0, stream>>>(xbf, wqkvT, qb, kb, vb);
  kv_kernel<<<512, 256, 0, stream>>>(kb, vb, kvw, ksumw);
  num_kernel<<<4096, 256, 0, stream>>>(qb, kvw, ksumw, attnb);
  gemm_out<<<256, 512, 0, stream>>>(attnb, woutT, b_out, out);
}

// Round 12
// 237.566 us; speedup vs baseline: 1.7600x; 1.2702x over previous
//
#include <hip/hip_runtime.h>
#include <hip/hip_bf16.h>

using bf16x8 = __bf16 __attribute__((ext_vector_type(8)));
using f32x4  = float  __attribute__((ext_vector_type(4)));
using u16x8  = unsigned short __attribute__((ext_vector_type(8)));
using u16x4  = unsigned short __attribute__((ext_vector_type(4)));

__device__ __forceinline__ unsigned short f2bf(float f) {
  unsigned u = __builtin_bit_cast(unsigned, f);
  u += 0x7fffu + ((u >> 16) & 1u);
  return (unsigned short)(u >> 16);
}
__device__ __forceinline__ float bf2f(unsigned short h) {
  return __builtin_bit_cast(float, (unsigned)h << 16);
}

__device__ __forceinline__ void gload16(const void* g, void* l) {
  __builtin_amdgcn_global_load_lds(
      (const __attribute__((address_space(1))) void*)g,
      (__attribute__((address_space(3))) void*)l, 16, 0, 0);
}

__device__ __forceinline__ void barrier_raw() {
  asm volatile("" ::: "memory");
  __builtin_amdgcn_s_barrier();
  asm volatile("" ::: "memory");
}
#define LGKM0() asm volatile("s_waitcnt lgkmcnt(0)" ::: "memory")
#define VMC6()  asm volatile("s_waitcnt vmcnt(6)" ::: "memory")
#define VMC0()  asm volatile("s_waitcnt vmcnt(0)" ::: "memory")

// ---------------- convert f32 -> bf16 (vectorized) ----------------
__global__ __launch_bounds__(256) void conv_f32_bf16(const float* __restrict__ in,
                                                     unsigned short* __restrict__ out, int n) {
  int stride = gridDim.x * 256 * 4;
  for (int i = (blockIdx.x * 256 + threadIdx.x) * 4; i < n; i += stride) {
    float4 v = *reinterpret_cast<const float4*>(in + i);
    u16x4 o = { f2bf(v.x), f2bf(v.y), f2bf(v.z), f2bf(v.w) };
    *reinterpret_cast<u16x4*>(out + i) = o;
  }
}

// ---------------- transpose + convert: out[c][r] = bf16(in[r][c]) ----------------
__global__ __launch_bounds__(256) void transpose_f32_bf16(const float* __restrict__ in,
                                                          unsigned short* __restrict__ out,
                                                          int R, int C) {
  __shared__ float t[64][65];
  int c0 = blockIdx.x * 64, r0 = blockIdx.y * 64;
  int lx = threadIdx.x & 63, ly = threadIdx.x >> 6;
#pragma unroll
  for (int i = 0; i < 16; ++i) {
    int r = ly * 16 + i;
    t[r][lx] = in[(size_t)(r0 + r) * C + c0 + lx];
  }
  __syncthreads();
#pragma unroll
  for (int i = 0; i < 16; ++i) {
    int c = ly * 16 + i;
    out[(size_t)(c0 + c) * R + r0 + lx] = f2bf(t[lx][c]);
  }
}

// ================= 256x256, BK=64, 8-wave, 8-phase GEMM mainloop =================
// EXACT round-5 configuration (best measured: qkv 136.8us, VGPR 116, no spill).
// Phase balance: Pa reads A m0-3 + B n0-1 (12), Pb reads B n2-3 (4),
// Pc reads A m4-7 (8), Pd reads 0. Stages: Pa->A-h1(t+1,nbuf), Pc->B-h0(t+2),
// Pd->B-h1(t+2)+A-h0(t+2). vmcnt(6) counted, never 0 in steady state.
__device__ __forceinline__ void gemm256_mainloop(
    const unsigned short* __restrict__ A, const unsigned short* __restrict__ Bt,
    int brow, int bcol, char* lds, f32x4 (&acc)[8][4]) {
  constexpr int NT = 16;  // K = 1024 / 64
  const int tid  = threadIdx.x;
  const int lane = tid & 63;
  const int w    = tid >> 6;
  const int wr   = w >> 2, wc = w & 3;
  const int lr   = lane & 15, kg = lane >> 4;

  const int o0 = tid * 16;
  const int o1 = 8192 + tid * 16;
  const int p0 = o0 ^ (((o0 >> 7) & 7) << 4);
  const int p1 = o1 ^ (((o1 >> 7) & 7) << 4);
  const int off0 = (p0 >> 7) * 2048 + (p0 & 127);
  const int off1 = (p1 >> 7) * 2048 + (p1 & 127);
  const int wq = w << 10;

  const int xr  = (lr & 7) << 4;
  const int ck0 = (kg * 16) ^ xr;
  const int ck1 = (64 + kg * 16) ^ xr;
  const int aoff = wr * 16384 + lr * 128;
  const int boff = 32768 + (wc >> 1) * 16384 + (wc & 1) * 8192 + lr * 128;

  auto STAGE = [&](const unsigned short* G, int rowbase, int t, int region) {
    const char* gb = (const char*)(G + (size_t)rowbase * 1024 + t * 64);
    char* lb = lds + region + wq;
    gload16(gb + off0, lb);
    gload16(gb + off1, lb + 8192);
  };

  // ---- prologue: tile0 full + 3 half-tiles of tile1 ----
  STAGE(Bt, bcol,       0, 32768);
  STAGE(Bt, bcol + 128, 0, 49152);
  STAGE(A,  brow,       0, 0);
  STAGE(A,  brow + 128, 0, 16384);
  STAGE(Bt, bcol,       1, 65536 + 32768);
  STAGE(Bt, bcol + 128, 1, 65536 + 49152);
  STAGE(A,  brow,       1, 65536);
  VMC6();
  barrier_raw();

  bf16x8 aF[4][2], bF[4][2];
  for (int t = 0; t < NT; ++t) {
    const int bufo  = (t & 1) << 16;
    const int nbufo = bufo ^ 65536;
    const char* LA = lds + bufo + aoff;
    const char* LB = lds + bufo + boff;

    // ---- Pa: read A m0-3 + B n0-1; stage A-h1(t+1)->nbuf; MFMA m0-3 x n0-1
#pragma unroll
    for (int n = 0; n < 2; ++n) {
      bF[n][0] = __builtin_bit_cast(bf16x8, *(const u16x8*)(LB + n * 2048 + ck0));
      bF[n][1] = __builtin_bit_cast(bf16x8, *(const u16x8*)(LB + n * 2048 + ck1));
    }
#pragma unroll
    for (int m = 0; m < 4; ++m) {
      aF[m][0] = __builtin_bit_cast(bf16x8, *(const u16x8*)(LA + m * 2048 + ck0));
      aF[m][1] = __builtin_bit_cast(bf16x8, *(const u16x8*)(LA + m * 2048 + ck1));
    }
    if (t + 1 < NT) STAGE(A, brow + 128, t + 1, nbufo + 16384);
    barrier_raw();
    LGKM0();
    __builtin_amdgcn_s_setprio(1);
#pragma unroll
    for (int kk = 0; kk < 2; ++kk)
#pragma unroll
      for (int m = 0; m < 4; ++m)
#pragma unroll
        for (int n = 0; n < 2; ++n)
          acc[m][n] = __builtin_amdgcn_mfma_f32_16x16x32_bf16(aF[m][kk], bF[n][kk], acc[m][n], 0, 0, 0);
    __builtin_amdgcn_s_setprio(0);
    barrier_raw();

    // ---- Pb: read B n2-3; MFMA m0-3 x n2-3
#pragma unroll
    for (int n = 2; n < 4; ++n) {
      bF[n][0] = __builtin_bit_cast(bf16x8, *(const u16x8*)(LB + n * 2048 + ck0));
      bF[n][1] = __builtin_bit_cast(bf16x8, *(const u16x8*)(LB + n * 2048 + ck1));
    }
    barrier_raw();
    LGKM0();
    __builtin_amdgcn_s_setprio(1);
#pragma unroll
    for (int kk = 0; kk < 2; ++kk)
#pragma unroll
      for (int m = 0; m < 4; ++m)
#pragma unroll
        for (int n = 2; n < 4; ++n)
          acc[m][n] = __builtin_amdgcn_mfma_f32_16x16x32_bf16(aF[m][kk], bF[n][kk], acc[m][n], 0, 0, 0);
    __builtin_amdgcn_s_setprio(0);
    barrier_raw();

    // ---- Pc: read A m4-7; stage B-h0(t+2); MFMA m4-7 x n2-3
#pragma unroll
    for (int m = 0; m < 4; ++m) {
      aF[m][0] = __builtin_bit_cast(bf16x8, *(const u16x8*)(LA + (m + 4) * 2048 + ck0));
      aF[m][1] = __builtin_bit_cast(bf16x8, *(const u16x8*)(LA + (m + 4) * 2048 + ck1));
    }
    if (t + 2 < NT) STAGE(Bt, bcol, t + 2, bufo + 32768);
    barrier_raw();
    LGKM0();
    __builtin_amdgcn_s_setprio(1);
#pragma unroll
    for (int kk = 0; kk < 2; ++kk)
#pragma unroll
      for (int m = 0; m < 4; ++m)
#pragma unroll
        for (int n = 2; n < 4; ++n)
          acc[m + 4][n] = __builtin_amdgcn_mfma_f32_16x16x32_bf16(aF[m][kk], bF[n][kk], acc[m + 4][n], 0, 0, 0);
    __builtin_amdgcn_s_setprio(0);
    barrier_raw();

    // ---- Pd: stage B-h1(t+2) + A-h0(t+2); MFMA m4-7 x n0-1; counted vmcnt
    if (t + 2 < NT) {
      STAGE(Bt, bcol + 128, t + 2, bufo + 49152);
      STAGE(A,  brow,       t + 2, bufo);
    }
    barrier_raw();
    __builtin_amdgcn_s_setprio(1);
#pragma unroll
    for (int kk = 0; kk < 2; ++kk)
#pragma unroll
      for (int m = 0; m < 4; ++m)
#pragma unroll
        for (int n = 0; n < 2; ++n)
          acc[m + 4][n] = __builtin_amdgcn_mfma_f32_16x16x32_bf16(aF[m][kk], bF[n][kk], acc[m + 4][n], 0, 0, 0);
    __builtin_amdgcn_s_setprio(0);
    if (t + 2 < NT) { VMC6(); } else { VMC0(); }
    barrier_raw();
  }
}

// ---------------- GEMM1: qkv = x @ W_qkv, epilogue elu+1 on q,k; scatter (B,H,N,D) ----------------
__global__ __launch_bounds__(512, 2) void gemm_qkv(
    const unsigned short* __restrict__ xbf, const unsigned short* __restrict__ wt,
    unsigned short* __restrict__ q, unsigned short* __restrict__ k, unsigned short* __restrict__ v) {
  __shared__ __align__(16) char lds[131072];
  f32x4 acc[8][4] = {};
  // L2-patch grid: XCD r owns tm stripe [8r,8r+8), tn-major within the stripe.
  const int bid = blockIdx.x;                    // 768 = 8 XCD x 8 tm x 12 tn
  const int r = bid & 7, i = bid >> 3;
  const int tm = r * 8 + (i & 7);
  const int tn = i >> 3;
  const int brow = tm * 256, bcol = tn * 256;
  gemm256_mainloop(xbf, wt, brow, bcol, lds, acc);

  const int lane = threadIdx.x & 63, w = threadIdx.x >> 6;
  const int wr = w >> 2, wc = w & 3;
  const int lr = lane & 15, kg = lane >> 4;
#pragma unroll
  for (int m = 0; m < 8; ++m)
#pragma unroll
    for (int n = 0; n < 4; ++n)
#pragma unroll
      for (int rr = 0; rr < 4; ++rr) {
        int grow = brow + wr * 128 + m * 16 + kg * 4 + rr;
        int gcol = bcol + wc * 64 + n * 16 + lr;
        float val = acc[m][n][rr];
        int tt = gcol >> 10;
        int h = (gcol >> 6) & 15;
        int d = gcol & 63;
        int b = grow >> 12, s = grow & 4095;
        size_t idx = ((size_t)(b * 16 + h) * 4096 + s) * 64 + d;
        if (tt < 2) {
          val = val > 0.f ? val + 1.f : __expf(val);  // elu(x)+1
          (tt == 0 ? q : k)[idx] = f2bf(val);
        } else {
          v[idx] = f2bf(val);
        }
      }
}

// ---------------- GEMM2: out = attn @ W_out + b ----------------
__global__ __launch_bounds__(512, 2) void gemm_out(
    const unsigned short* __restrict__ attn, const unsigned short* __restrict__ wt,
    const float* __restrict__ bias, float* __restrict__ out) {
  __shared__ __align__(16) char lds[131072];
  f32x4 acc[8][4] = {};
  const int bid = blockIdx.x;                    // 256 = 8 XCD x 8 tm x 4 tn
  const int r = bid & 7, i = bid >> 3;
  const int tm = r * 8 + (i & 7);
  const int tn = i >> 3;
  const int brow = tm * 256, bcol = tn * 256;
  gemm256_mainloop(attn, wt, brow, bcol, lds, acc);

  const int lane = threadIdx.x & 63, w = threadIdx.x >> 6;
  const int wr = w >> 2, wc = w & 3;
  const int lr = lane & 15, kg = lane >> 4;
#pragma unroll
  for (int m = 0; m < 8; ++m)
#pragma unroll
    for (int n = 0; n < 4; ++n)
#pragma unroll
      for (int rr = 0; rr < 4; ++rr) {
        int grow = brow + wr * 128 + m * 16 + kg * 4 + rr;
        int gcol = bcol + wc * 64 + n * 16 + lr;
        out[(size_t)grow * 1024 + gcol] = acc[m][n][rr] + bias[gcol];
      }
}

// ======== kv via MFMA: kv[e][d] = sum_n v[n][e] k[n][d]; ksum[d] = sum_n k[n][d] ========
// 256 blocks = (head bh, n-half). Per 64-n subtile: stage k,v tiles TRANSPOSED in LDS
// (kt[d][n ^ ((d>>3&7)<<3)], stride 72 -> writes/reads both <=2-way bank aliasing,
// b128 16B-aligned), then mfma_16x16x32 with A=v_t (a[j]=v[n0+kg*8+j][e=w*16+lr]),
// B=k_t (b[j]=k[n0+kg*8+j][d=dt*16+lr]). ksum via all-ones A-fragment on wave 0
// (D rows all equal sum_n k[n][d]). Global loads prefetched one subtile ahead (T14).
// Partial outputs per n-half (plain stores, no atomics/memset); num_kernel sums 2.
__global__ __launch_bounds__(256) void kv_mfma(
    const unsigned short* __restrict__ k, const unsigned short* __restrict__ v,
    float* __restrict__ kv_part, float* __restrict__ ksum_part) {
  const int bid = blockIdx.x;             // 256 = 128 heads x 2 halves
  const int bh = bid >> 1, half = bid & 1;
  const size_t nbase = (size_t)bh * 4096 + half * 2048;
  __shared__ unsigned short kt[64 * 72];
  __shared__ unsigned short vt[64 * 72];
  const int tid  = threadIdx.x;
  const int lane = tid & 63, w = tid >> 6;
  const int lr = lane & 15, kg = lane >> 4;
  const int srow = w * 16 + (lane >> 2);   // staging n-row within subtile
  const int sd   = (lane & 3) * 16;        // staging d-block

  f32x4 acc[4] = {{0.f,0.f,0.f,0.f},{0.f,0.f,0.f,0.f},{0.f,0.f,0.f,0.f},{0.f,0.f,0.f,0.f}};
  f32x4 ks[4]  = {{0.f,0.f,0.f,0.f},{0.f,0.f,0.f,0.f},{0.f,0.f,0.f,0.f},{0.f,0.f,0.f,0.f}};
  const u16x8 onesu = { 0x3F80,0x3F80,0x3F80,0x3F80,0x3F80,0x3F80,0x3F80,0x3F80 };
  const bf16x8 aone = __builtin_bit_cast(bf16x8, onesu);

  // read-side fragment addresses (elems): row*72 + (nlocal ^ ((row>>3&7)<<3))
  const int arow = w * 16 + lr;                         // e-row for A (v_t)
  const int axor = ((arow >> 3) & 7) << 3;
  const unsigned short* aB[2];
  aB[0] = vt + arow * 72 + ((kg * 8) ^ axor);
  aB[1] = vt + arow * 72 + ((32 + kg * 8) ^ axor);
  const unsigned short* bB[4][2];
#pragma unroll
  for (int dt = 0; dt < 4; ++dt) {
    int drow = dt * 16 + lr;
    int dxor = ((drow >> 3) & 7) << 3;
    bB[dt][0] = kt + drow * 72 + ((kg * 8) ^ dxor);
    bB[dt][1] = kt + drow * 72 + ((32 + kg * 8) ^ dxor);
  }

  u16x8 pk0, pk1, pv0, pv1;
  auto LOADR = [&](int sub) {
    const unsigned short* kr = k + (nbase + (size_t)sub * 64 + srow) * 64 + sd;
    const unsigned short* vr = v + (nbase + (size_t)sub * 64 + srow) * 64 + sd;
    pk0 = *(const u16x8*)kr;  pk1 = *(const u16x8*)(kr + 8);
    pv0 = *(const u16x8*)vr;  pv1 = *(const u16x8*)(vr + 8);
  };
  LOADR(0);

  for (int sub = 0; sub < 32; ++sub) {
    __syncthreads();                       // prior subtile's frag reads done
    u16x8 k0 = pk0, k1 = pk1, v0 = pv0, v1 = pv1;
#pragma unroll
    for (int j = 0; j < 8; ++j) {
      int d0 = sd + j, d1 = sd + 8 + j;
      int x0 = ((d0 >> 3) & 7) << 3, x1 = ((d1 >> 3) & 7) << 3;
      kt[d0 * 72 + (srow ^ x0)] = k0[j];
      kt[d1 * 72 + (srow ^ x1)] = k1[j];
      vt[d0 * 72 + (srow ^ x0)] = v0[j];
      vt[d1 * 72 + (srow ^ x1)] = v1[j];
    }
    if (sub + 1 < 32) LOADR(sub + 1);      // prefetch hides under barrier+MFMA
    __syncthreads();
#pragma unroll
    for (int kk = 0; kk < 2; ++kk) {
      bf16x8 af = __builtin_bit_cast(bf16x8, *(const u16x8*)aB[kk]);
#pragma unroll
      for (int dt = 0; dt < 4; ++dt) {
        bf16x8 bf = __builtin_bit_cast(bf16x8, *(const u16x8*)bB[dt][kk]);
        acc[dt] = __builtin_amdgcn_mfma_f32_16x16x32_bf16(af, bf, acc[dt], 0, 0, 0);
        if (w == 0)
          ks[dt] = __builtin_amdgcn_mfma_f32_16x16x32_bf16(aone, bf, ks[dt], 0, 0, 0);
      }
    }
  }

  float* kvp = kv_part + ((size_t)half * 128 + bh) * 4096;
#pragma unroll
  for (int dt = 0; dt < 4; ++dt)
#pragma unroll
    for (int r = 0; r < 4; ++r) {
      int e = w * 16 + kg * 4 + r;
      kvp[e * 64 + dt * 16 + lr] = acc[dt][r];
    }
  if (w == 0 && kg == 0) {
    float* ksp = ksum_part + (size_t)half * 8192 + bh * 64;
#pragma unroll
    for (int dt = 0; dt < 4; ++dt) ksp[dt * 16 + lr] = ks[dt][0];
  }
}

// ---------------- num = q @ kv ; attn = num / (q.ksum + 1e-6) ----------------
__global__ __launch_bounds__(256) void num_kernel(
    const unsigned short* __restrict__ q, const float* __restrict__ kv_part,
    const float* __restrict__ ksum_part, unsigned short* __restrict__ attn) {
  const int bid = blockIdx.x;              // B*H*64 = 4096
  const int bh = bid >> 6, sblk = bid & 63;
  const int b = bh >> 4, h = bh & 15;
  __shared__ unsigned short kvs[64 * 72];
  __shared__ float ksum_s[64];
  __shared__ float norm_s[64];
  const int tid = threadIdx.x;
  const float* kv0 = kv_part + (size_t)bh * 4096;
  const float* kv1 = kv_part + (size_t)(128 + bh) * 4096;
#pragma unroll
  for (int r = 0; r < 4; ++r) {
    int e = r * 1024 + tid * 4;
    float4 f0 = *reinterpret_cast<const float4*>(&kv0[e]);
    float4 f1 = *reinterpret_cast<const float4*>(&kv1[e]);
    float4 f = { f0.x + f1.x, f0.y + f1.y, f0.z + f1.z, f0.w + f1.w };
    int row = e >> 6, col = e & 63;
    u16x4 o = { f2bf(f.x), f2bf(f.y), f2bf(f.z), f2bf(f.w) };
    *reinterpret_cast<u16x4*>(&kvs[row * 72 + col]) = o;
  }
  if (tid < 16) {
    float4 f0 = *reinterpret_cast<const float4*>(&ksum_part[bh * 64 + tid * 4]);
    float4 f1 = *reinterpret_cast<const float4*>(&ksum_part[8192 + bh * 64 + tid * 4]);
    ksum_s[tid * 4 + 0] = f0.x + f1.x; ksum_s[tid * 4 + 1] = f0.y + f1.y;
    ksum_s[tid * 4 + 2] = f0.z + f1.z; ksum_s[tid * 4 + 3] = f0.w + f1.w;
  }
  __syncthreads();

  const int lane = tid & 63, w = tid >> 6;
  const int lr = lane & 15, kg = lane >> 4;
  const int s0 = sblk * 64 + w * 16;
  const unsigned short* qrow = q + ((size_t)bh * 4096 + s0 + lr) * 64 + kg * 8;
  u16x8 a0u = *reinterpret_cast<const u16x8*>(qrow);
  u16x8 a1u = *reinterpret_cast<const u16x8*>(qrow + 32);
  bf16x8 a0 = __builtin_bit_cast(bf16x8, a0u);
  bf16x8 a1 = __builtin_bit_cast(bf16x8, a1u);

  float p = 0.f;
#pragma unroll
  for (int j = 0; j < 8; ++j) {
    p += bf2f(a0u[j]) * ksum_s[kg * 8 + j];
    p += bf2f(a1u[j]) * ksum_s[32 + kg * 8 + j];
  }
  p += __shfl_xor(p, 16);
  p += __shfl_xor(p, 32);
  if (kg == 0) norm_s[w * 16 + lr] = p;

  f32x4 accs[4];
#pragma unroll
  for (int jf = 0; jf < 4; ++jf) {
    u16x8 b0u = *reinterpret_cast<const u16x8*>(&kvs[(jf * 16 + lr) * 72 + kg * 8]);
    u16x8 b1u = *reinterpret_cast<const u16x8*>(&kvs[(jf * 16 + lr) * 72 + 32 + kg * 8]);
    f32x4 c = {0.f, 0.f, 0.f, 0.f};
    c = __builtin_amdgcn_mfma_f32_16x16x32_bf16(a0, __builtin_bit_cast(bf16x8, b0u), c, 0, 0, 0);
    c = __builtin_amdgcn_mfma_f32_16x16x32_bf16(a1, __builtin_bit_cast(bf16x8, b1u), c, 0, 0, 0);
    accs[jf] = c;
  }
  float dn[4];
#pragma unroll
  for (int r = 0; r < 4; ++r) dn[r] = norm_s[w * 16 + kg * 4 + r] + 1e-6f;

  unsigned short* ab = attn + (size_t)b * 4096 * 1024 + h * 64;
#pragma unroll
  for (int jf = 0; jf < 4; ++jf)
#pragma unroll
    for (int r = 0; r < 4; ++r) {
      int s = s0 + kg * 4 + r;
      int e2 = jf * 16 + lr;
      ab[(size_t)s * 1024 + e2] = f2bf(accs[jf][r] / dn[r]);
    }
}

extern "C" void kernel_launch(void* const* d_in, const int* in_sizes, int n_in,
                              void* d_out, int out_size, void* d_ws, size_t ws_size,
                              hipStream_t stream) {
  const float* x     = (const float*)d_in[0];
  const float* W_qkv = (const float*)d_in[1];
  const float* W_out = (const float*)d_in[2];
  const float* b_out = (const float*)d_in[3];
  float* out = (float*)d_out;

  unsigned short* xbf   = (unsigned short*)d_ws;            // 16384*1024
  unsigned short* attnb = xbf;                               // alias (xbf dead after gemm_qkv)
  unsigned short* wqkvT = xbf + 16777216;                    // 3072*1024
  unsigned short* woutT = wqkvT + 3145728;                   // 1024*1024
  unsigned short* qb    = woutT + 1048576;                   // 16777216
  unsigned short* kb    = qb + 16777216;
  unsigned short* vb    = kb + 16777216;
  float* kvp            = (float*)(vb + 16777216);           // 2*128*4096 f32 (partials)
  float* ksp            = kvp + 1048576;                     // 2*8192 f32

  conv_f32_bf16<<<2048, 256, 0, stream>>>(x, xbf, 16777216);
  transpose_f32_bf16<<<dim3(48, 16), 256, 0, stream>>>(W_qkv, wqkvT, 1024, 3072);
  transpose_f32_bf16<<<dim3(16, 16), 256, 0, stream>>>(W_out, woutT, 1024, 1024);
  gemm_qkv<<<768, 512, 0, stream>>>(xbf, wqkvT, qb, kb, vb);
  kv_mfma<<<256, 256, 0, stream>>>(kb, vb, kvp, ksp);
  num_kernel<<<4096, 256, 0, stream>>>(qb, kvp, ksp, attnb);
  gemm_out<<<256, 512, 0, stream>>>(attnb, woutT, b_out, out);
}

// Round 13
// 230.031 us; speedup vs baseline: 1.8177x; 1.0328x over previous
//
#include <hip/hip_runtime.h>
#include <hip/hip_bf16.h>

using bf16x8 = __bf16 __attribute__((ext_vector_type(8)));
using f32x4  = float  __attribute__((ext_vector_type(4)));
using u16x8  = unsigned short __attribute__((ext_vector_type(8)));
using u16x4  = unsigned short __attribute__((ext_vector_type(4)));

__device__ __forceinline__ unsigned short f2bf(float f) {
  unsigned u = __builtin_bit_cast(unsigned, f);
  u += 0x7fffu + ((u >> 16) & 1u);
  return (unsigned short)(u >> 16);
}
__device__ __forceinline__ float bf2f(unsigned short h) {
  return __builtin_bit_cast(float, (unsigned)h << 16);
}

__device__ __forceinline__ void gload16(const void* g, void* l) {
  __builtin_amdgcn_global_load_lds(
      (const __attribute__((address_space(1))) void*)g,
      (__attribute__((address_space(3))) void*)l, 16, 0, 0);
}

__device__ __forceinline__ void barrier_raw() {
  asm volatile("" ::: "memory");
  __builtin_amdgcn_s_barrier();
  asm volatile("" ::: "memory");
}
#define LGKM0() asm volatile("s_waitcnt lgkmcnt(0)" ::: "memory")
#define LGKM8() asm volatile("s_waitcnt lgkmcnt(8)" ::: "memory")
#define VMC6()  asm volatile("s_waitcnt vmcnt(6)" ::: "memory")
#define VMC0()  asm volatile("s_waitcnt vmcnt(0)" ::: "memory")

// ---------------- fused prep: conv x->bf16 + transpose W_qkv + transpose W_out ----------------
// grid: [0,2048) conv | [2048,2816) W_qkv 48x16 | [2816,3072) W_out 16x16
__global__ __launch_bounds__(256) void prep_kernel(
    const float* __restrict__ x, unsigned short* __restrict__ xbf,
    const float* __restrict__ Wqkv, unsigned short* __restrict__ wqkvT,
    const float* __restrict__ Wout, unsigned short* __restrict__ woutT) {
  __shared__ float t[64][65];
  const int bid = blockIdx.x;
  if (bid < 2048) {
    int stride = 2048 * 256 * 8;
    for (int i = (bid * 256 + threadIdx.x) * 8; i < 16777216; i += stride) {
      float4 v0 = *reinterpret_cast<const float4*>(x + i);
      float4 v1 = *reinterpret_cast<const float4*>(x + i + 4);
      u16x8 o = { f2bf(v0.x), f2bf(v0.y), f2bf(v0.z), f2bf(v0.w),
                  f2bf(v1.x), f2bf(v1.y), f2bf(v1.z), f2bf(v1.w) };
      *reinterpret_cast<u16x8*>(xbf + i) = o;
    }
    return;
  }
  const float* in;
  unsigned short* out;
  int R, C, bx, by;
  if (bid < 2816) {
    in = Wqkv; out = wqkvT; R = 1024; C = 3072;
    bx = (bid - 2048) % 48; by = (bid - 2048) / 48;
  } else {
    in = Wout; out = woutT; R = 1024; C = 1024;
    bx = (bid - 2816) % 16; by = (bid - 2816) / 16;
  }
  int c0 = bx * 64, r0 = by * 64;
  int lx = threadIdx.x & 63, ly = threadIdx.x >> 6;
#pragma unroll
  for (int i = 0; i < 16; ++i) {
    int r = ly * 16 + i;
    t[r][lx] = in[(size_t)(r0 + r) * C + c0 + lx];
  }
  __syncthreads();
#pragma unroll
  for (int i = 0; i < 16; ++i) {
    int c = ly * 16 + i;
    out[(size_t)(c0 + c) * R + r0 + lx] = f2bf(t[lx][c]);
  }
}

// ================= 256x256, BK=64, 8-wave, 8-phase GEMM mainloop =================
// Round-5 configuration (best measured: qkv 136.8us, VGPR 116, no spill) +
// m201's partial lgkm pre-drain in Pa (the 12-read phase).
__device__ __forceinline__ void gemm256_mainloop(
    const unsigned short* __restrict__ A, const unsigned short* __restrict__ Bt,
    int brow, int bcol, char* lds, f32x4 (&acc)[8][4]) {
  constexpr int NT = 16;  // K = 1024 / 64
  const int tid  = threadIdx.x;
  const int lane = tid & 63;
  const int w    = tid >> 6;
  const int wr   = w >> 2, wc = w & 3;
  const int lr   = lane & 15, kg = lane >> 4;

  const int o0 = tid * 16;
  const int o1 = 8192 + tid * 16;
  const int p0 = o0 ^ (((o0 >> 7) & 7) << 4);
  const int p1 = o1 ^ (((o1 >> 7) & 7) << 4);
  const int off0 = (p0 >> 7) * 2048 + (p0 & 127);
  const int off1 = (p1 >> 7) * 2048 + (p1 & 127);
  const int wq = w << 10;

  const int xr  = (lr & 7) << 4;
  const int ck0 = (kg * 16) ^ xr;
  const int ck1 = (64 + kg * 16) ^ xr;
  const int aoff = wr * 16384 + lr * 128;
  const int boff = 32768 + (wc >> 1) * 16384 + (wc & 1) * 8192 + lr * 128;

  auto STAGE = [&](const unsigned short* G, int rowbase, int t, int region) {
    const char* gb = (const char*)(G + (size_t)rowbase * 1024 + t * 64);
    char* lb = lds + region + wq;
    gload16(gb + off0, lb);
    gload16(gb + off1, lb + 8192);
  };

  // ---- prologue: tile0 full + 3 half-tiles of tile1 ----
  STAGE(Bt, bcol,       0, 32768);
  STAGE(Bt, bcol + 128, 0, 49152);
  STAGE(A,  brow,       0, 0);
  STAGE(A,  brow + 128, 0, 16384);
  STAGE(Bt, bcol,       1, 65536 + 32768);
  STAGE(Bt, bcol + 128, 1, 65536 + 49152);
  STAGE(A,  brow,       1, 65536);
  VMC6();
  barrier_raw();

  bf16x8 aF[4][2], bF[4][2];
  for (int t = 0; t < NT; ++t) {
    const int bufo  = (t & 1) << 16;
    const int nbufo = bufo ^ 65536;
    const char* LA = lds + bufo + aoff;
    const char* LB = lds + bufo + boff;

    // ---- Pa: read A m0-3 + B n0-1 (12); stage A-h1(t+1)->nbuf; MFMA m0-3 x n0-1
#pragma unroll
    for (int n = 0; n < 2; ++n) {
      bF[n][0] = __builtin_bit_cast(bf16x8, *(const u16x8*)(LB + n * 2048 + ck0));
      bF[n][1] = __builtin_bit_cast(bf16x8, *(const u16x8*)(LB + n * 2048 + ck1));
    }
#pragma unroll
    for (int m = 0; m < 4; ++m) {
      aF[m][0] = __builtin_bit_cast(bf16x8, *(const u16x8*)(LA + m * 2048 + ck0));
      aF[m][1] = __builtin_bit_cast(bf16x8, *(const u16x8*)(LA + m * 2048 + ck1));
    }
    if (t + 1 < NT) STAGE(A, brow + 128, t + 1, nbufo + 16384);
    LGKM8();   // pre-drain first 4 of 12 reads (m201 trick) before the barrier
    barrier_raw();
    LGKM0();
    __builtin_amdgcn_s_setprio(1);
#pragma unroll
    for (int kk = 0; kk < 2; ++kk)
#pragma unroll
      for (int m = 0; m < 4; ++m)
#pragma unroll
        for (int n = 0; n < 2; ++n)
          acc[m][n] = __builtin_amdgcn_mfma_f32_16x16x32_bf16(aF[m][kk], bF[n][kk], acc[m][n], 0, 0, 0);
    __builtin_amdgcn_s_setprio(0);
    barrier_raw();

    // ---- Pb: read B n2-3; MFMA m0-3 x n2-3
#pragma unroll
    for (int n = 2; n < 4; ++n) {
      bF[n][0] = __builtin_bit_cast(bf16x8, *(const u16x8*)(LB + n * 2048 + ck0));
      bF[n][1] = __builtin_bit_cast(bf16x8, *(const u16x8*)(LB + n * 2048 + ck1));
    }
    barrier_raw();
    LGKM0();
    __builtin_amdgcn_s_setprio(1);
#pragma unroll
    for (int kk = 0; kk < 2; ++kk)
#pragma unroll
      for (int m = 0; m < 4; ++m)
#pragma unroll
        for (int n = 2; n < 4; ++n)
          acc[m][n] = __builtin_amdgcn_mfma_f32_16x16x32_bf16(aF[m][kk], bF[n][kk], acc[m][n], 0, 0, 0);
    __builtin_amdgcn_s_setprio(0);
    barrier_raw();

    // ---- Pc: read A m4-7; stage B-h0(t+2); MFMA m4-7 x n2-3
#pragma unroll
    for (int m = 0; m < 4; ++m) {
      aF[m][0] = __builtin_bit_cast(bf16x8, *(const u16x8*)(LA + (m + 4) * 2048 + ck0));
      aF[m][1] = __builtin_bit_cast(bf16x8, *(const u16x8*)(LA + (m + 4) * 2048 + ck1));
    }
    if (t + 2 < NT) STAGE(Bt, bcol, t + 2, bufo + 32768);
    barrier_raw();
    LGKM0();
    __builtin_amdgcn_s_setprio(1);
#pragma unroll
    for (int kk = 0; kk < 2; ++kk)
#pragma unroll
      for (int m = 0; m < 4; ++m)
#pragma unroll
        for (int n = 2; n < 4; ++n)
          acc[m + 4][n] = __builtin_amdgcn_mfma_f32_16x16x32_bf16(aF[m][kk], bF[n][kk], acc[m + 4][n], 0, 0, 0);
    __builtin_amdgcn_s_setprio(0);
    barrier_raw();

    // ---- Pd: stage B-h1(t+2) + A-h0(t+2); MFMA m4-7 x n0-1; counted vmcnt
    if (t + 2 < NT) {
      STAGE(Bt, bcol + 128, t + 2, bufo + 49152);
      STAGE(A,  brow,       t + 2, bufo);
    }
    barrier_raw();
    __builtin_amdgcn_s_setprio(1);
#pragma unroll
    for (int kk = 0; kk < 2; ++kk)
#pragma unroll
      for (int m = 0; m < 4; ++m)
#pragma unroll
        for (int n = 0; n < 2; ++n)
          acc[m + 4][n] = __builtin_amdgcn_mfma_f32_16x16x32_bf16(aF[m][kk], bF[n][kk], acc[m + 4][n], 0, 0, 0);
    __builtin_amdgcn_s_setprio(0);
    if (t + 2 < NT) { VMC6(); } else { VMC0(); }
    barrier_raw();
  }
}

// ---------------- GEMM1: qkv = x @ W_qkv, epilogue elu+1 on q,k; scatter (B,H,N,D) ----------------
__global__ __launch_bounds__(512, 2) void gemm_qkv(
    const unsigned short* __restrict__ xbf, const unsigned short* __restrict__ wt,
    unsigned short* __restrict__ q, unsigned short* __restrict__ k, unsigned short* __restrict__ v) {
  __shared__ __align__(16) char lds[131072];
  f32x4 acc[8][4] = {};
  // L2-patch grid: XCD r owns tm stripe [8r,8r+8), tn-major within the stripe.
  const int bid = blockIdx.x;                    // 768 = 8 XCD x 8 tm x 12 tn
  const int r = bid & 7, i = bid >> 3;
  const int tm = r * 8 + (i & 7);
  const int tn = i >> 3;
  const int brow = tm * 256, bcol = tn * 256;
  gemm256_mainloop(xbf, wt, brow, bcol, lds, acc);

  const int lane = threadIdx.x & 63, w = threadIdx.x >> 6;
  const int wr = w >> 2, wc = w & 3;
  const int lr = lane & 15, kg = lane >> 4;
#pragma unroll
  for (int m = 0; m < 8; ++m)
#pragma unroll
    for (int n = 0; n < 4; ++n)
#pragma unroll
      for (int rr = 0; rr < 4; ++rr) {
        int grow = brow + wr * 128 + m * 16 + kg * 4 + rr;
        int gcol = bcol + wc * 64 + n * 16 + lr;
        float val = acc[m][n][rr];
        int tt = gcol >> 10;
        int h = (gcol >> 6) & 15;
        int d = gcol & 63;
        int b = grow >> 12, s = grow & 4095;
        size_t idx = ((size_t)(b * 16 + h) * 4096 + s) * 64 + d;
        if (tt < 2) {
          val = val > 0.f ? val + 1.f : __expf(val);  // elu(x)+1
          (tt == 0 ? q : k)[idx] = f2bf(val);
        } else {
          v[idx] = f2bf(val);
        }
      }
}

// ---------------- GEMM2: out = attn @ W_out + b ----------------
__global__ __launch_bounds__(512, 2) void gemm_out(
    const unsigned short* __restrict__ attn, const unsigned short* __restrict__ wt,
    const float* __restrict__ bias, float* __restrict__ out) {
  __shared__ __align__(16) char lds[131072];
  f32x4 acc[8][4] = {};
  const int bid = blockIdx.x;                    // 256 = 8 XCD x 8 tm x 4 tn
  const int r = bid & 7, i = bid >> 3;
  const int tm = r * 8 + (i & 7);
  const int tn = i >> 3;
  const int brow = tm * 256, bcol = tn * 256;
  gemm256_mainloop(attn, wt, brow, bcol, lds, acc);

  const int lane = threadIdx.x & 63, w = threadIdx.x >> 6;
  const int wr = w >> 2, wc = w & 3;
  const int lr = lane & 15, kg = lane >> 4;
#pragma unroll
  for (int m = 0; m < 8; ++m)
#pragma unroll
    for (int n = 0; n < 4; ++n)
#pragma unroll
      for (int rr = 0; rr < 4; ++rr) {
        int grow = brow + wr * 128 + m * 16 + kg * 4 + rr;
        int gcol = bcol + wc * 64 + n * 16 + lr;
        out[(size_t)grow * 1024 + gcol] = acc[m][n][rr] + bias[gcol];
      }
}

// ======== kv via MFMA: kv[e][d] = sum_n v[n][e] k[n][d]; ksum[d] = sum_n k[n][d] ========
__global__ __launch_bounds__(256) void kv_mfma(
    const unsigned short* __restrict__ k, const unsigned short* __restrict__ v,
    float* __restrict__ kv_part, float* __restrict__ ksum_part) {
  const int bid = blockIdx.x;             // 256 = 128 heads x 2 halves
  const int bh = bid >> 1, half = bid & 1;
  const size_t nbase = (size_t)bh * 4096 + half * 2048;
  __shared__ unsigned short kt[64 * 72];
  __shared__ unsigned short vt[64 * 72];
  const int tid  = threadIdx.x;
  const int lane = tid & 63, w = tid >> 6;
  const int lr = lane & 15, kg = lane >> 4;
  const int srow = w * 16 + (lane >> 2);
  const int sd   = (lane & 3) * 16;

  f32x4 acc[4] = {{0.f,0.f,0.f,0.f},{0.f,0.f,0.f,0.f},{0.f,0.f,0.f,0.f},{0.f,0.f,0.f,0.f}};
  f32x4 ks[4]  = {{0.f,0.f,0.f,0.f},{0.f,0.f,0.f,0.f},{0.f,0.f,0.f,0.f},{0.f,0.f,0.f,0.f}};
  const u16x8 onesu = { 0x3F80,0x3F80,0x3F80,0x3F80,0x3F80,0x3F80,0x3F80,0x3F80 };
  const bf16x8 aone = __builtin_bit_cast(bf16x8, onesu);

  const int arow = w * 16 + lr;
  const int axor = ((arow >> 3) & 7) << 3;
  const unsigned short* aB[2];
  aB[0] = vt + arow * 72 + ((kg * 8) ^ axor);
  aB[1] = vt + arow * 72 + ((32 + kg * 8) ^ axor);
  const unsigned short* bB[4][2];
#pragma unroll
  for (int dt = 0; dt < 4; ++dt) {
    int drow = dt * 16 + lr;
    int dxor = ((drow >> 3) & 7) << 3;
    bB[dt][0] = kt + drow * 72 + ((kg * 8) ^ dxor);
    bB[dt][1] = kt + drow * 72 + ((32 + kg * 8) ^ dxor);
  }

  u16x8 pk0, pk1, pv0, pv1;
  auto LOADR = [&](int sub) {
    const unsigned short* kr = k + (nbase + (size_t)sub * 64 + srow) * 64 + sd;
    const unsigned short* vr = v + (nbase + (size_t)sub * 64 + srow) * 64 + sd;
    pk0 = *(const u16x8*)kr;  pk1 = *(const u16x8*)(kr + 8);
    pv0 = *(const u16x8*)vr;  pv1 = *(const u16x8*)(vr + 8);
  };
  LOADR(0);

  for (int sub = 0; sub < 32; ++sub) {
    __syncthreads();
    u16x8 k0 = pk0, k1 = pk1, v0 = pv0, v1 = pv1;
#pragma unroll
    for (int j = 0; j < 8; ++j) {
      int d0 = sd + j, d1 = sd + 8 + j;
      int x0 = ((d0 >> 3) & 7) << 3, x1 = ((d1 >> 3) & 7) << 3;
      kt[d0 * 72 + (srow ^ x0)] = k0[j];
      kt[d1 * 72 + (srow ^ x1)] = k1[j];
      vt[d0 * 72 + (srow ^ x0)] = v0[j];
      vt[d1 * 72 + (srow ^ x1)] = v1[j];
    }
    if (sub + 1 < 32) LOADR(sub + 1);
    __syncthreads();
#pragma unroll
    for (int kk = 0; kk < 2; ++kk) {
      bf16x8 af = __builtin_bit_cast(bf16x8, *(const u16x8*)aB[kk]);
#pragma unroll
      for (int dt = 0; dt < 4; ++dt) {
        bf16x8 bf = __builtin_bit_cast(bf16x8, *(const u16x8*)bB[dt][kk]);
        acc[dt] = __builtin_amdgcn_mfma_f32_16x16x32_bf16(af, bf, acc[dt], 0, 0, 0);
        if (w == 0)
          ks[dt] = __builtin_amdgcn_mfma_f32_16x16x32_bf16(aone, bf, ks[dt], 0, 0, 0);
      }
    }
  }

  float* kvp = kv_part + ((size_t)half * 128 + bh) * 4096;
#pragma unroll
  for (int dt = 0; dt < 4; ++dt)
#pragma unroll
    for (int r = 0; r < 4; ++r) {
      int e = w * 16 + kg * 4 + r;
      kvp[e * 64 + dt * 16 + lr] = acc[dt][r];
    }
  if (w == 0 && kg == 0) {
    float* ksp = ksum_part + (size_t)half * 8192 + bh * 64;
#pragma unroll
    for (int dt = 0; dt < 4; ++dt) ksp[dt * 16 + lr] = ks[dt][0];
  }
}

// ---------------- num = q @ kv ; attn = num / (q.ksum + 1e-6) ----------------
__global__ __launch_bounds__(256) void num_kernel(
    const unsigned short* __restrict__ q, const float* __restrict__ kv_part,
    const float* __restrict__ ksum_part, unsigned short* __restrict__ attn) {
  const int bid = blockIdx.x;              // B*H*64 = 4096
  const int bh = bid >> 6, sblk = bid & 63;
  const int b = bh >> 4, h = bh & 15;
  __shared__ unsigned short kvs[64 * 72];
  __shared__ float ksum_s[64];
  __shared__ float norm_s[64];
  const int tid = threadIdx.x;
  const float* kv0 = kv_part + (size_t)bh * 4096;
  const float* kv1 = kv_part + (size_t)(128 + bh) * 4096;
#pragma unroll
  for (int r = 0; r < 4; ++r) {
    int e = r * 1024 + tid * 4;
    float4 f0 = *reinterpret_cast<const float4*>(&kv0[e]);
    float4 f1 = *reinterpret_cast<const float4*>(&kv1[e]);
    float4 f = { f0.x + f1.x, f0.y + f1.y, f0.z + f1.z, f0.w + f1.w };
    int row = e >> 6, col = e & 63;
    u16x4 o = { f2bf(f.x), f2bf(f.y), f2bf(f.z), f2bf(f.w) };
    *reinterpret_cast<u16x4*>(&kvs[row * 72 + col]) = o;
  }
  if (tid < 16) {
    float4 f0 = *reinterpret_cast<const float4*>(&ksum_part[bh * 64 + tid * 4]);
    float4 f1 = *reinterpret_cast<const float4*>(&ksum_part[8192 + bh * 64 + tid * 4]);
    ksum_s[tid * 4 + 0] = f0.x + f1.x; ksum_s[tid * 4 + 1] = f0.y + f1.y;
    ksum_s[tid * 4 + 2] = f0.z + f1.z; ksum_s[tid * 4 + 3] = f0.w + f1.w;
  }
  __syncthreads();

  const int lane = tid & 63, w = tid >> 6;
  const int lr = lane & 15, kg = lane >> 4;
  const int s0 = sblk * 64 + w * 16;
  const unsigned short* qrow = q + ((size_t)bh * 4096 + s0 + lr) * 64 + kg * 8;
  u16x8 a0u = *reinterpret_cast<const u16x8*>(qrow);
  u16x8 a1u = *reinterpret_cast<const u16x8*>(qrow + 32);
  bf16x8 a0 = __builtin_bit_cast(bf16x8, a0u);
  bf16x8 a1 = __builtin_bit_cast(bf16x8, a1u);

  float p = 0.f;
#pragma unroll
  for (int j = 0; j < 8; ++j) {
    p += bf2f(a0u[j]) * ksum_s[kg * 8 + j];
    p += bf2f(a1u[j]) * ksum_s[32 + kg * 8 + j];
  }
  p += __shfl_xor(p, 16);
  p += __shfl_xor(p, 32);
  if (kg == 0) norm_s[w * 16 + lr] = p;

  f32x4 accs[4];
#pragma unroll
  for (int jf = 0; jf < 4; ++jf) {
    u16x8 b0u = *reinterpret_cast<const u16x8*>(&kvs[(jf * 16 + lr) * 72 + kg * 8]);
    u16x8 b1u = *reinterpret_cast<const u16x8*>(&kvs[(jf * 16 + lr) * 72 + 32 + kg * 8]);
    f32x4 c = {0.f, 0.f, 0.f, 0.f};
    c = __builtin_amdgcn_mfma_f32_16x16x32_bf16(a0, __builtin_bit_cast(bf16x8, b0u), c, 0, 0, 0);
    c = __builtin_amdgcn_mfma_f32_16x16x32_bf16(a1, __builtin_bit_cast(bf16x8, b1u), c, 0, 0, 0);
    accs[jf] = c;
  }
  float dn[4];
#pragma unroll
  for (int r = 0; r < 4; ++r) dn[r] = norm_s[w * 16 + kg * 4 + r] + 1e-6f;

  unsigned short* ab = attn + (size_t)b * 4096 * 1024 + h * 64;
#pragma unroll
  for (int jf = 0; jf < 4; ++jf)
#pragma unroll
    for (int r = 0; r < 4; ++r) {
      int s = s0 + kg * 4 + r;
      int e2 = jf * 16 + lr;
      ab[(size_t)s * 1024 + e2] = f2bf(accs[jf][r] / dn[r]);
    }
}

extern "C" void kernel_launch(void* const* d_in, const int* in_sizes, int n_in,
                              void* d_out, int out_size, void* d_ws, size_t ws_size,
                              hipStream_t stream) {
  const float* x     = (const float*)d_in[0];
  const float* W_qkv = (const float*)d_in[1];
  const float* W_out = (const float*)d_in[2];
  const float* b_out = (const float*)d_in[3];
  float* out = (float*)d_out;

  unsigned short* xbf   = (unsigned short*)d_ws;            // 16384*1024
  unsigned short* attnb = xbf;                               // alias (xbf dead after gemm_qkv)
  unsigned short* wqkvT = xbf + 16777216;                    // 3072*1024
  unsigned short* woutT = wqkvT + 3145728;                   // 1024*1024
  unsigned short* qb    = woutT + 1048576;                   // 16777216
  unsigned short* kb    = qb + 16777216;
  unsigned short* vb    = kb + 16777216;
  float* kvp            = (float*)(vb + 16777216);           // 2*128*4096 f32 (partials)
  float* ksp            = kvp + 1048576;                     // 2*8192 f32

  prep_kernel<<<3072, 256, 0, stream>>>(x, xbf, W_qkv, wqkvT, W_out, woutT);
  gemm_qkv<<<768, 512, 0, stream>>>(xbf, wqkvT, qb, kb, vb);
  kv_mfma<<<256, 256, 0, stream>>>(kb, vb, kvp, ksp);
  num_kernel<<<4096, 256, 0, stream>>>(qb, kvp, ksp, attnb);
  gemm_out<<<256, 512, 0, stream>>>(attnb, woutT, b_out, out);
}